// Round 2
// baseline (1159.358 us; speedup 1.0000x reference)
//
#include <hip/hip_runtime.h>
#include <hip/hip_bf16.h>

#define NB 8
#define NC 256
#define NHW 4096       // H*W
#define HDIM 64
#define WDIM 64
#define NHEAD 8
#define NKD 32
#define NAG 64
#define NMIP 8
#define EPSF 1e-5f
#define FSCALE 0.17677669529663687f  // 32^-0.5

// ---------------- K1: qkv = BN(w_qkv @ x) ----------------
// per batch: [768,256] x [256,4096]; 64x64 tile, 256 thr, 4x4 micro
__global__ __launch_bounds__(256) void k_qkv(const float* __restrict__ x,
                                             const float* __restrict__ w,
                                             const float* __restrict__ bnp,
                                             float* __restrict__ Q,
                                             float* __restrict__ K,
                                             float* __restrict__ V) {
    const int b = blockIdx.z;
    const int ocB = blockIdx.y * 64;
    const int nB  = blockIdx.x * 64;
    const int tid = threadIdx.x;
    const int tx = tid & 15, ty = tid >> 4;
    __shared__ float As[64][33];
    __shared__ float Bs[32][65];
    float acc[4][4] = {};
    for (int k0 = 0; k0 < 256; k0 += 32) {
        for (int i = tid; i < 64 * 32; i += 256) {
            int r = i >> 5, c = i & 31;
            As[r][c] = w[(ocB + r) * 256 + k0 + c];
        }
        for (int i = tid; i < 32 * 64; i += 256) {
            int r = i >> 6, c = i & 63;
            Bs[r][c] = x[((size_t)b * NC + k0 + r) * NHW + nB + c];
        }
        __syncthreads();
        #pragma unroll
        for (int kk = 0; kk < 32; ++kk) {
            float av[4], bv[4];
            #pragma unroll
            for (int i = 0; i < 4; ++i) av[i] = As[ty * 4 + i][kk];
            #pragma unroll
            for (int j = 0; j < 4; ++j) bv[j] = Bs[kk][tx * 4 + j];
            #pragma unroll
            for (int i = 0; i < 4; ++i)
                #pragma unroll
                for (int j = 0; j < 4; ++j)
                    acc[i][j] = fmaf(av[i], bv[j], acc[i][j]);
        }
        __syncthreads();
    }
    #pragma unroll
    for (int i = 0; i < 4; ++i) {
        int oc = ocB + ty * 4 + i;
        float g = bnp[0 * 768 + oc], be = bnp[1 * 768 + oc];
        float m = bnp[2 * 768 + oc], vv = bnp[3 * 768 + oc];
        float inv = g * rsqrtf(vv + EPSF);
        float bias = be - m * inv;
        float* dst; int oc2;
        if (oc < 256)      { dst = Q; oc2 = oc; }
        else if (oc < 512) { dst = K; oc2 = oc - 256; }
        else               { dst = V; oc2 = oc - 512; }
        #pragma unroll
        for (int j = 0; j < 4; ++j) {
            int n = nB + tx * 4 + j;
            dst[((size_t)b * NC + oc2) * NHW + n] = acc[i][j] * inv + bias;
        }
    }
}

// ---------------- K2a: SE gates per (b,h) ----------------
__global__ __launch_bounds__(256) void k_gates(const float* __restrict__ K,
                                               const float* __restrict__ V,
                                               const float* __restrict__ w1,
                                               const float* __restrict__ bn1,
                                               const float* __restrict__ w2,
                                               const float* __restrict__ bn2,
                                               float* __restrict__ GK,
                                               float* __restrict__ GV) {
    const int b = blockIdx.x >> 6;
    const int h = blockIdx.x & 63;
    const int c = threadIdx.x;
    __shared__ float am[NC];
    __shared__ float m1[NMIP];
    for (int pass = 0; pass < 2; ++pass) {
        const float* src = pass ? V : K;
        const float* row = src + ((size_t)b * NC + c) * NHW + h * WDIM;
        float s = 0.f;
        for (int w = 0; w < WDIM; ++w) s += row[w];
        am[c] = s * (1.0f / WDIM);
        __syncthreads();
        if (c < NMIP) {
            float t = 0.f;
            for (int cc = 0; cc < NC; ++cc) t += w1[c * NC + cc] * am[cc];
            float g = bn1[0 * NMIP + c], be = bn1[1 * NMIP + c];
            float mm = bn1[2 * NMIP + c], vv = bn1[3 * NMIP + c];
            float inv = g * rsqrtf(vv + EPSF);
            m1[c] = t * inv + (be - mm * inv);
        }
        __syncthreads();
        {
            float t = 0.f;
            #pragma unroll
            for (int j = 0; j < NMIP; ++j) t += w2[c * NMIP + j] * m1[j];
            float g = bn2[0 * NC + c], be = bn2[1 * NC + c];
            float mm = bn2[2 * NC + c], vv = bn2[3 * NC + c];
            float inv = g * rsqrtf(vv + EPSF);
            (pass ? GV : GK)[((size_t)b * NC + c) * HDIM + h] = t * inv + (be - mm * inv);
        }
        __syncthreads();
    }
}

// ---------------- K2b: apply gates ----------------
__global__ __launch_bounds__(256) void k_apply_gates(float* __restrict__ K,
                                                     float* __restrict__ V,
                                                     const float* __restrict__ GK,
                                                     const float* __restrict__ GV) {
    const size_t total = (size_t)NB * NC * NHW;
    for (size_t i = (size_t)blockIdx.x * 256 + threadIdx.x; i < total;
         i += (size_t)gridDim.x * 256) {
        size_t bc = i >> 12;
        int n = (int)(i & 4095);
        int h = n >> 6;
        K[i] *= GK[bc * HDIM + h];
        V[i] *= GV[bc * HDIM + h];
    }
}

// ---------------- K3: 8x8 block pool of Q -> agent tokens ----------------
__global__ __launch_bounds__(64) void k_pool(const float* __restrict__ Q,
                                             float* __restrict__ A_) {
    const int bc = blockIdx.x;       // b*NC + c
    const int ag = threadIdx.x;      // 0..63
    const int ph = ag >> 3, pw = ag & 7;
    const float* src = Q + (size_t)bc * NHW;
    float s = 0.f;
    #pragma unroll
    for (int i = 0; i < 8; ++i)
        #pragma unroll
        for (int j = 0; j < 8; ++j)
            s += src[(ph * 8 + i) * WDIM + pw * 8 + j];
    A_[(size_t)bc * NAG + ag] = s * (1.0f / 64.0f);
}

// ---------------- K4: agent attn = softmax_n(a^T k)*v^T, flash-style ----------------
// block per (b,head); 256 thr: ag = tid>>2, jg = tid&3
__global__ __launch_bounds__(256) void k_attn(const float* __restrict__ K,
                                              const float* __restrict__ V,
                                              const float* __restrict__ A_,
                                              float* __restrict__ AT) {
    const int b = blockIdx.x >> 3;
    const int h = blockIdx.x & 7;
    const int tid = threadIdx.x;
    const int ag = tid >> 2;
    const int jg = tid & 3;      // also the d-group in PV phase
    __shared__ float kt[32][65];
    __shared__ float vt[32][65];
    __shared__ float p_s[64][65];
    __shared__ float m_s[64], l_s[64], f_s[64];

    float a_col[32];
    #pragma unroll
    for (int d = 0; d < 32; ++d)
        a_col[d] = A_[((size_t)(b * NC + h * NKD + d)) * NAG + ag] * FSCALE;

    float accr[8];
    #pragma unroll
    for (int i = 0; i < 8; ++i) accr[i] = 0.f;
    if (tid < NAG) { m_s[tid] = -1e30f; l_s[tid] = 0.f; }
    __syncthreads();

    const float* Kp = K + (size_t)(b * NC + h * NKD) * NHW;
    const float* Vp = V + (size_t)(b * NC + h * NKD) * NHW;

    for (int nt = 0; nt < NHW / 64; ++nt) {
        for (int i = tid; i < 32 * 64; i += 256) {
            int r = i >> 6, cc = i & 63;
            kt[r][cc] = Kp[(size_t)r * NHW + nt * 64 + cc];
            vt[r][cc] = Vp[(size_t)r * NHW + nt * 64 + cc];
        }
        __syncthreads();
        // scores: this thread covers j = jg*16 .. jg*16+15 for its ag row
        float sreg[16];
        float smax = -1e30f;
        #pragma unroll
        for (int jj = 0; jj < 16; ++jj) {
            int j = jg * 16 + jj;
            float s = 0.f;
            #pragma unroll
            for (int d = 0; d < 32; ++d) s = fmaf(a_col[d], kt[d][j], s);
            sreg[jj] = s;
            smax = fmaxf(smax, s);
        }
        smax = fmaxf(smax, __shfl_xor(smax, 1));
        smax = fmaxf(smax, __shfl_xor(smax, 2));
        float mold = m_s[ag];
        float mnew = fmaxf(mold, smax);
        float psum = 0.f;
        #pragma unroll
        for (int jj = 0; jj < 16; ++jj) {
            float p = __expf(sreg[jj] - mnew);
            p_s[ag][jg * 16 + jj] = p;
            psum += p;
        }
        psum += __shfl_xor(psum, 1);
        psum += __shfl_xor(psum, 2);
        if (jg == 0) {
            float f = __expf(mold - mnew);
            f_s[ag] = f;
            l_s[ag] = l_s[ag] * f + psum;
            m_s[ag] = mnew;
        }
        __syncthreads();
        // PV: acc[ag][d] for d in jg*8..+8
        float f = f_s[ag];
        #pragma unroll
        for (int i = 0; i < 8; ++i) accr[i] *= f;
        for (int j = 0; j < 64; ++j) {
            float pj = p_s[ag][j];
            #pragma unroll
            for (int i = 0; i < 8; ++i)
                accr[i] = fmaf(pj, vt[jg * 8 + i][j], accr[i]);
        }
        __syncthreads();
    }
    float linv = 1.0f / l_s[ag];
    #pragma unroll
    for (int i = 0; i < 8; ++i)
        AT[((size_t)(b * NHEAD + h) * NAG + ag) * NKD + jg * 8 + i] = accr[i] * linv;
}

// ---------------- K5: out1 = softmax_ag(q^T a) @ attn ----------------
// one thread per (b, head, n)
__global__ __launch_bounds__(256) void k_qattn(const float* __restrict__ Q,
                                               const float* __restrict__ A_,
                                               const float* __restrict__ AT,
                                               float* __restrict__ O1) {
    const int b = blockIdx.z, h = blockIdx.y;
    const int n = blockIdx.x * 256 + threadIdx.x;
    __shared__ float a_s[NKD][NAG + 1];
    __shared__ float at_s[NAG][NKD];
    for (int i = threadIdx.x; i < NKD * NAG; i += 256) {
        int d = i >> 6, ag = i & 63;
        a_s[d][ag] = A_[((size_t)(b * NC + h * NKD + d)) * NAG + ag] * FSCALE;
    }
    for (int i = threadIdx.x; i < NAG * NKD; i += 256)
        at_s[i >> 5][i & 31] = AT[(size_t)(b * NHEAD + h) * NAG * NKD + i];
    __syncthreads();

    float q[32];
    const float* qp = Q + ((size_t)b * NC + h * NKD) * NHW + n;
    #pragma unroll
    for (int d = 0; d < 32; ++d) q[d] = qp[(size_t)d * NHW];

    float s[64];
    float mx = -1e30f;
    #pragma unroll
    for (int ag = 0; ag < 64; ++ag) {
        float t = 0.f;
        #pragma unroll
        for (int d = 0; d < 32; ++d) t = fmaf(q[d], a_s[d][ag], t);
        s[ag] = t;
        mx = fmaxf(mx, t);
    }
    float out[32];
    #pragma unroll
    for (int d = 0; d < 32; ++d) out[d] = 0.f;
    float l = 0.f;
    #pragma unroll
    for (int ag = 0; ag < 64; ++ag) {
        float p = __expf(s[ag] - mx);
        l += p;
        #pragma unroll
        for (int d = 0; d < 32; ++d) out[d] = fmaf(p, at_s[ag][d], out[d]);
    }
    float rl = 1.0f / l;
    float* op = O1 + ((size_t)b * NC + h * NKD) * NHW + n;
    #pragma unroll
    for (int d = 0; d < 32; ++d) op[(size_t)d * NHW] = out[d] * rl;
}

// ---------------- K6: O1 += BN(depthwise 3x3 conv of V) ----------------
__global__ __launch_bounds__(256) void k_pe(const float* __restrict__ V,
                                            const float* __restrict__ wpe,
                                            const float* __restrict__ bnp,
                                            float* __restrict__ O1) {
    const int bc = blockIdx.x;
    const int c = bc & (NC - 1);
    float wreg[9];
    #pragma unroll
    for (int i = 0; i < 9; ++i) wreg[i] = wpe[c * 9 + i];
    float g = bnp[0 * NC + c], be = bnp[1 * NC + c];
    float m = bnp[2 * NC + c], vv = bnp[3 * NC + c];
    float inv = g * rsqrtf(vv + EPSF);
    float bias = be - m * inv;
    const float* src = V + (size_t)bc * NHW;
    float* dst = O1 + (size_t)bc * NHW;
    for (int idx = threadIdx.x; idx < NHW; idx += 256) {
        int h = idx >> 6, w = idx & 63;
        float s = 0.f;
        #pragma unroll
        for (int kh = 0; kh < 3; ++kh) {
            int hh = h + kh - 1;
            if (hh < 0 || hh >= HDIM) continue;
            #pragma unroll
            for (int kw = 0; kw < 3; ++kw) {
                int ww = w + kw - 1;
                if (ww < 0 || ww >= WDIM) continue;
                s = fmaf(wreg[kh * 3 + kw], src[hh * WDIM + ww], s);
            }
        }
        dst[idx] += s * inv + bias;
    }
}

// ---------------- K7: out = BN(w_proj @ O1) ----------------
__global__ __launch_bounds__(256) void k_proj(const float* __restrict__ O1,
                                              const float* __restrict__ w,
                                              const float* __restrict__ bnp,
                                              float* __restrict__ out) {
    const int b = blockIdx.z;
    const int ocB = blockIdx.y * 64;
    const int nB  = blockIdx.x * 64;
    const int tid = threadIdx.x;
    const int tx = tid & 15, ty = tid >> 4;
    __shared__ float As[64][33];
    __shared__ float Bs[32][65];
    float acc[4][4] = {};
    for (int k0 = 0; k0 < 256; k0 += 32) {
        for (int i = tid; i < 64 * 32; i += 256) {
            int r = i >> 5, c = i & 31;
            As[r][c] = w[(ocB + r) * 256 + k0 + c];
        }
        for (int i = tid; i < 32 * 64; i += 256) {
            int r = i >> 6, c = i & 63;
            Bs[r][c] = O1[((size_t)b * NC + k0 + r) * NHW + nB + c];
        }
        __syncthreads();
        #pragma unroll
        for (int kk = 0; kk < 32; ++kk) {
            float av[4], bv[4];
            #pragma unroll
            for (int i = 0; i < 4; ++i) av[i] = As[ty * 4 + i][kk];
            #pragma unroll
            for (int j = 0; j < 4; ++j) bv[j] = Bs[kk][tx * 4 + j];
            #pragma unroll
            for (int i = 0; i < 4; ++i)
                #pragma unroll
                for (int j = 0; j < 4; ++j)
                    acc[i][j] = fmaf(av[i], bv[j], acc[i][j]);
        }
        __syncthreads();
    }
    #pragma unroll
    for (int i = 0; i < 4; ++i) {
        int oc = ocB + ty * 4 + i;
        float g = bnp[0 * NC + oc], be = bnp[1 * NC + oc];
        float m = bnp[2 * NC + oc], vv = bnp[3 * NC + oc];
        float inv = g * rsqrtf(vv + EPSF);
        float bias = be - m * inv;
        #pragma unroll
        for (int j = 0; j < 4; ++j) {
            int n = nB + tx * 4 + j;
            out[((size_t)b * NC + oc) * NHW + n] = acc[i][j] * inv + bias;
        }
    }
}

extern "C" void kernel_launch(void* const* d_in, const int* in_sizes, int n_in,
                              void* d_out, int out_size, void* d_ws, size_t ws_size,
                              hipStream_t stream) {
    (void)in_sizes; (void)n_in; (void)out_size; (void)ws_size;
    const float* x       = (const float*)d_in[0];
    const float* w_qkv   = (const float*)d_in[1];
    const float* bn_qkv  = (const float*)d_in[2];
    const float* w_cv1   = (const float*)d_in[3];
    const float* bn_cv1  = (const float*)d_in[4];
    const float* w_cv2   = (const float*)d_in[5];
    const float* bn_cv2  = (const float*)d_in[6];
    const float* w_proj  = (const float*)d_in[7];
    const float* bn_proj = (const float*)d_in[8];
    const float* w_pe    = (const float*)d_in[9];
    const float* bn_pe   = (const float*)d_in[10];
    float* out = (float*)d_out;

    float* ws = (float*)d_ws;
    const size_t SZ = (size_t)NB * NC * NHW;           // 8,388,608 floats
    float* Q  = ws;
    float* Kb = ws + SZ;
    float* Vb = ws + 2 * SZ;
    float* O1 = Kb;                                    // K dead after k_attn
    float* Aa = ws + 3 * SZ;
    float* AT = Aa + (size_t)NB * NC * NAG;            // 131072
    float* GK = AT + (size_t)NB * NHEAD * NAG * NKD;   // 131072
    float* GV = GK + (size_t)NB * NC * HDIM;           // 131072

    k_qkv<<<dim3(64, 12, NB), 256, 0, stream>>>(x, w_qkv, bn_qkv, Q, Kb, Vb);
    k_gates<<<NB * HDIM, 256, 0, stream>>>(Kb, Vb, w_cv1, bn_cv1, w_cv2, bn_cv2, GK, GV);
    k_apply_gates<<<2048, 256, 0, stream>>>(Kb, Vb, GK, GV);
    k_pool<<<NB * NC, 64, 0, stream>>>(Q, Aa);
    k_attn<<<NB * NHEAD, 256, 0, stream>>>(Kb, Vb, Aa, AT);
    k_qattn<<<dim3(16, NHEAD, NB), 256, 0, stream>>>(Q, Aa, AT, O1);
    k_pe<<<NB * NC, 256, 0, stream>>>(Vb, w_pe, bn_pe, O1);
    k_proj<<<dim3(64, 4, NB), 256, 0, stream>>>(O1, w_proj, bn_proj, out);
}

// Round 3
// 662.047 us; speedup vs baseline: 1.7512x; 1.7512x over previous
//
#include <hip/hip_runtime.h>
#include <hip/hip_bf16.h>

#define NB 8
#define NC 256
#define NHW 4096       // H*W
#define HDIM 64
#define WDIM 64
#define NHEAD 8
#define NKD 32
#define NAG 64
#define NMIP 8
#define NSPLIT 16
#define EPSF 1e-5f
#define FSCALE 0.17677669529663687f  // 32^-0.5

// ---------------- K1: qkv = BN(w_qkv @ x) ----------------
__global__ __launch_bounds__(256) void k_qkv(const float* __restrict__ x,
                                             const float* __restrict__ w,
                                             const float* __restrict__ bnp,
                                             float* __restrict__ Q,
                                             float* __restrict__ K,
                                             float* __restrict__ V) {
    const int b = blockIdx.z;
    const int ocB = blockIdx.y * 64;
    const int nB  = blockIdx.x * 64;
    const int tid = threadIdx.x;
    const int tx = tid & 15, ty = tid >> 4;
    __shared__ float As[64][33];
    __shared__ float Bs[32][65];
    float acc[4][4] = {};
    for (int k0 = 0; k0 < 256; k0 += 32) {
        for (int i = tid; i < 64 * 32; i += 256) {
            int r = i >> 5, c = i & 31;
            As[r][c] = w[(ocB + r) * 256 + k0 + c];
        }
        for (int i = tid; i < 32 * 64; i += 256) {
            int r = i >> 6, c = i & 63;
            Bs[r][c] = x[((size_t)b * NC + k0 + r) * NHW + nB + c];
        }
        __syncthreads();
        #pragma unroll
        for (int kk = 0; kk < 32; ++kk) {
            float av[4], bv[4];
            #pragma unroll
            for (int i = 0; i < 4; ++i) av[i] = As[ty * 4 + i][kk];
            #pragma unroll
            for (int j = 0; j < 4; ++j) bv[j] = Bs[kk][tx * 4 + j];
            #pragma unroll
            for (int i = 0; i < 4; ++i)
                #pragma unroll
                for (int j = 0; j < 4; ++j)
                    acc[i][j] = fmaf(av[i], bv[j], acc[i][j]);
        }
        __syncthreads();
    }
    #pragma unroll
    for (int i = 0; i < 4; ++i) {
        int oc = ocB + ty * 4 + i;
        float g = bnp[0 * 768 + oc], be = bnp[1 * 768 + oc];
        float m = bnp[2 * 768 + oc], vv = bnp[3 * 768 + oc];
        float inv = g * rsqrtf(vv + EPSF);
        float bias = be - m * inv;
        float* dst; int oc2;
        if (oc < 256)      { dst = Q; oc2 = oc; }
        else if (oc < 512) { dst = K; oc2 = oc - 256; }
        else               { dst = V; oc2 = oc - 512; }
        #pragma unroll
        for (int j = 0; j < 4; ++j) {
            int n = nB + tx * 4 + j;
            dst[((size_t)b * NC + oc2) * NHW + n] = acc[i][j] * inv + bias;
        }
    }
}

// ---------------- K2: SE gates per (b,h), fused in-place apply ----------------
__global__ __launch_bounds__(256) void k_gates(float* __restrict__ K,
                                               float* __restrict__ V,
                                               const float* __restrict__ w1,
                                               const float* __restrict__ bn1,
                                               const float* __restrict__ w2,
                                               const float* __restrict__ bn2) {
    const int b = blockIdx.x >> 6;
    const int h = blockIdx.x & 63;
    const int c = threadIdx.x;
    __shared__ float am[NC];
    __shared__ float m1[NMIP];
    for (int pass = 0; pass < 2; ++pass) {
        float* src = pass ? V : K;
        float* row = src + ((size_t)b * NC + c) * NHW + h * WDIM;
        float s = 0.f;
        for (int w = 0; w < WDIM; ++w) s += row[w];
        am[c] = s * (1.0f / WDIM);
        __syncthreads();
        if (c < NMIP) {
            float t = 0.f;
            for (int cc = 0; cc < NC; ++cc) t += w1[c * NC + cc] * am[cc];
            float g = bn1[0 * NMIP + c], be = bn1[1 * NMIP + c];
            float mm = bn1[2 * NMIP + c], vv = bn1[3 * NMIP + c];
            float inv = g * rsqrtf(vv + EPSF);
            m1[c] = t * inv + (be - mm * inv);
        }
        __syncthreads();
        {
            float t = 0.f;
            #pragma unroll
            for (int j = 0; j < NMIP; ++j) t += w2[c * NMIP + j] * m1[j];
            float g = bn2[0 * NC + c], be = bn2[1 * NC + c];
            float mm = bn2[2 * NC + c], vv = bn2[3 * NC + c];
            float inv = g * rsqrtf(vv + EPSF);
            float gate = t * inv + (be - mm * inv);
            for (int w = 0; w < WDIM; ++w) row[w] *= gate;
        }
        __syncthreads();
    }
}

// ---------------- K3: 8x8 block pool of Q -> agent tokens ----------------
__global__ __launch_bounds__(64) void k_pool(const float* __restrict__ Q,
                                             float* __restrict__ A_) {
    const int bc = blockIdx.x;       // b*NC + c
    const int ag = threadIdx.x;      // 0..63
    const int ph = ag >> 3, pw = ag & 7;
    const float* src = Q + (size_t)bc * NHW;
    float s = 0.f;
    #pragma unroll
    for (int i = 0; i < 8; ++i)
        #pragma unroll
        for (int j = 0; j < 8; ++j)
            s += src[(ph * 8 + i) * WDIM + pw * 8 + j];
    A_[(size_t)bc * NAG + ag] = s * (1.0f / 64.0f);
}

// ---------------- K4a: agent attn partials (split-N flash) ----------------
// grid = NB*NHEAD*NSPLIT; 256 thr: agq = tid>>4 (4 ags), jq = tid&15 (4 js / 2 ds)
__global__ __launch_bounds__(256) void k_attn_part(const float* __restrict__ K,
                                                   const float* __restrict__ V,
                                                   const float* __restrict__ A_,
                                                   float* __restrict__ Pm,
                                                   float* __restrict__ Pl,
                                                   float* __restrict__ Pacc) {
    const int bh = blockIdx.x >> 4;
    const int ns = blockIdx.x & (NSPLIT - 1);
    const int b = bh >> 3, h = bh & 7;
    const int tid = threadIdx.x;
    const int agq = tid >> 4;
    const int jq  = tid & 15;
    __shared__ float a_s[32][64];
    __shared__ float kt[32][64];
    __shared__ float vt_t[64][34];
    __shared__ float p_s[64][68];

    for (int i = tid; i < 32 * 64; i += 256) {
        int d = i >> 6, ag = i & 63;
        a_s[d][ag] = A_[((size_t)(b * NC + h * NKD + d)) * NAG + ag] * FSCALE;
    }

    float mrow[4], lrow[4], acc[4][2];
    #pragma unroll
    for (int i = 0; i < 4; ++i) {
        mrow[i] = -1e30f; lrow[i] = 0.f; acc[i][0] = 0.f; acc[i][1] = 0.f;
    }

    const int ncols = NHW / NSPLIT;                 // 256
    const float* Kp = K + (size_t)(b * NC + h * NKD) * NHW + ns * ncols;
    const float* Vp = V + (size_t)(b * NC + h * NKD) * NHW + ns * ncols;

    for (int nt = 0; nt < ncols / 64; ++nt) {       // 4 tiles
        for (int i = tid; i < 32 * 64; i += 256) {
            int r = i >> 6, cc = i & 63;
            kt[r][cc]   = Kp[(size_t)r * NHW + nt * 64 + cc];
            vt_t[cc][r] = Vp[(size_t)r * NHW + nt * 64 + cc];
        }
        __syncthreads();

        // scores 4x4 micro: s[i][jj] = sum_d a[d][agq*4+i] * k[d][jq*4+jj]
        float s[4][4] = {};
        #pragma unroll
        for (int kk = 0; kk < 32; ++kk) {
            float4 av = *reinterpret_cast<const float4*>(&a_s[kk][agq * 4]);
            float4 kv = *reinterpret_cast<const float4*>(&kt[kk][jq * 4]);
            float aa[4] = {av.x, av.y, av.z, av.w};
            float bb[4] = {kv.x, kv.y, kv.z, kv.w};
            #pragma unroll
            for (int i = 0; i < 4; ++i)
                #pragma unroll
                for (int jj = 0; jj < 4; ++jj)
                    s[i][jj] = fmaf(aa[i], bb[jj], s[i][jj]);
        }
        // per-ag-row max across jj then across the 16 jq lanes
        float f[4];
        #pragma unroll
        for (int i = 0; i < 4; ++i) {
            float pm = fmaxf(fmaxf(s[i][0], s[i][1]), fmaxf(s[i][2], s[i][3]));
            pm = fmaxf(pm, __shfl_xor(pm, 1));
            pm = fmaxf(pm, __shfl_xor(pm, 2));
            pm = fmaxf(pm, __shfl_xor(pm, 4));
            pm = fmaxf(pm, __shfl_xor(pm, 8));
            float mnew = fmaxf(mrow[i], pm);
            f[i] = __expf(mrow[i] - mnew);
            mrow[i] = mnew;
            float ps = 0.f;
            #pragma unroll
            for (int jj = 0; jj < 4; ++jj) {
                float p = __expf(s[i][jj] - mnew);
                p_s[jq * 4 + jj][agq * 4 + i] = p;
                ps += p;
            }
            ps += __shfl_xor(ps, 1);
            ps += __shfl_xor(ps, 2);
            ps += __shfl_xor(ps, 4);
            ps += __shfl_xor(ps, 8);
            lrow[i] = lrow[i] * f[i] + ps;
            acc[i][0] *= f[i];
            acc[i][1] *= f[i];
        }
        __syncthreads();

        // PV: thread (agq, jq): out[agq*4+i][jq*2+dd] += p[ag][j] * v[d][j]
        #pragma unroll 4
        for (int j = 0; j < 64; ++j) {
            float4 pv = *reinterpret_cast<const float4*>(&p_s[j][agq * 4]);
            float2 vv = *reinterpret_cast<const float2*>(&vt_t[j][jq * 2]);
            float pp[4] = {pv.x, pv.y, pv.z, pv.w};
            #pragma unroll
            for (int i = 0; i < 4; ++i) {
                acc[i][0] = fmaf(pp[i], vv.x, acc[i][0]);
                acc[i][1] = fmaf(pp[i], vv.y, acc[i][1]);
            }
        }
        __syncthreads();
    }

    const size_t pbase = (size_t)(bh * NSPLIT + ns) * NAG;
    #pragma unroll
    for (int i = 0; i < 4; ++i) {
        int ag = agq * 4 + i;
        #pragma unroll
        for (int dd = 0; dd < 2; ++dd)
            Pacc[(pbase + ag) * NKD + jq * 2 + dd] = acc[i][dd];
        if (jq == 0) {
            Pm[pbase + ag] = mrow[i];
            Pl[pbase + ag] = lrow[i];
        }
    }
}

// ---------------- K4b: combine partials ----------------
__global__ __launch_bounds__(256) void k_attn_comb(const float* __restrict__ Pm,
                                                   const float* __restrict__ Pl,
                                                   const float* __restrict__ Pacc,
                                                   float* __restrict__ AT) {
    const int bh = blockIdx.x;
    const int tid = threadIdx.x;
    const int ag = tid >> 2, jg = tid & 3;
    float m = -1e30f;
    #pragma unroll
    for (int ns = 0; ns < NSPLIT; ++ns)
        m = fmaxf(m, Pm[(size_t)(bh * NSPLIT + ns) * NAG + ag]);
    float l = 0.f;
    float acc[8] = {};
    for (int ns = 0; ns < NSPLIT; ++ns) {
        size_t pb = (size_t)(bh * NSPLIT + ns) * NAG + ag;
        float f = __expf(Pm[pb] - m);
        l += Pl[pb] * f;
        const float* pp = Pacc + pb * NKD + jg * 8;
        #pragma unroll
        for (int i = 0; i < 8; ++i) acc[i] += pp[i] * f;
    }
    float linv = 1.0f / l;
    #pragma unroll
    for (int i = 0; i < 8; ++i)
        AT[((size_t)bh * NAG + ag) * NKD + jg * 8 + i] = acc[i] * linv;
}

// ---------------- K5: out1 = softmax_ag(q^T a) @ attn ----------------
__global__ __launch_bounds__(256) void k_qattn(const float* __restrict__ Q,
                                               const float* __restrict__ A_,
                                               const float* __restrict__ AT,
                                               float* __restrict__ O1) {
    const int b = blockIdx.z, h = blockIdx.y;
    const int n = blockIdx.x * 256 + threadIdx.x;
    __shared__ float a_s[NKD][NAG + 1];
    __shared__ float at_s[NAG][NKD];
    for (int i = threadIdx.x; i < NKD * NAG; i += 256) {
        int d = i >> 6, ag = i & 63;
        a_s[d][ag] = A_[((size_t)(b * NC + h * NKD + d)) * NAG + ag] * FSCALE;
    }
    for (int i = threadIdx.x; i < NAG * NKD; i += 256)
        at_s[i >> 5][i & 31] = AT[(size_t)(b * NHEAD + h) * NAG * NKD + i];
    __syncthreads();

    float q[32];
    const float* qp = Q + ((size_t)b * NC + h * NKD) * NHW + n;
    #pragma unroll
    for (int d = 0; d < 32; ++d) q[d] = qp[(size_t)d * NHW];

    float s[64];
    float mx = -1e30f;
    #pragma unroll
    for (int ag = 0; ag < 64; ++ag) {
        float t = 0.f;
        #pragma unroll
        for (int d = 0; d < 32; ++d) t = fmaf(q[d], a_s[d][ag], t);
        s[ag] = t;
        mx = fmaxf(mx, t);
    }
    float out[32];
    #pragma unroll
    for (int d = 0; d < 32; ++d) out[d] = 0.f;
    float l = 0.f;
    #pragma unroll
    for (int ag = 0; ag < 64; ++ag) {
        float p = __expf(s[ag] - mx);
        l += p;
        #pragma unroll
        for (int d = 0; d < 32; ++d) out[d] = fmaf(p, at_s[ag][d], out[d]);
    }
    float rl = 1.0f / l;
    float* op = O1 + ((size_t)b * NC + h * NKD) * NHW + n;
    #pragma unroll
    for (int d = 0; d < 32; ++d) op[(size_t)d * NHW] = out[d] * rl;
}

// ---------------- K6: O1 += BN(depthwise 3x3 conv of V) ----------------
__global__ __launch_bounds__(256) void k_pe(const float* __restrict__ V,
                                            const float* __restrict__ wpe,
                                            const float* __restrict__ bnp,
                                            float* __restrict__ O1) {
    const int bc = blockIdx.x;
    const int c = bc & (NC - 1);
    float wreg[9];
    #pragma unroll
    for (int i = 0; i < 9; ++i) wreg[i] = wpe[c * 9 + i];
    float g = bnp[0 * NC + c], be = bnp[1 * NC + c];
    float m = bnp[2 * NC + c], vv = bnp[3 * NC + c];
    float inv = g * rsqrtf(vv + EPSF);
    float bias = be - m * inv;
    const float* src = V + (size_t)bc * NHW;
    float* dst = O1 + (size_t)bc * NHW;
    for (int idx = threadIdx.x; idx < NHW; idx += 256) {
        int h = idx >> 6, w = idx & 63;
        float s = 0.f;
        #pragma unroll
        for (int kh = 0; kh < 3; ++kh) {
            int hh = h + kh - 1;
            if (hh < 0 || hh >= HDIM) continue;
            #pragma unroll
            for (int kw = 0; kw < 3; ++kw) {
                int ww = w + kw - 1;
                if (ww < 0 || ww >= WDIM) continue;
                s = fmaf(wreg[kh * 3 + kw], src[hh * WDIM + ww], s);
            }
        }
        dst[idx] += s * inv + bias;
    }
}

// ---------------- K7: out = BN(w_proj @ O1) ----------------
__global__ __launch_bounds__(256) void k_proj(const float* __restrict__ O1,
                                              const float* __restrict__ w,
                                              const float* __restrict__ bnp,
                                              float* __restrict__ out) {
    const int b = blockIdx.z;
    const int ocB = blockIdx.y * 64;
    const int nB  = blockIdx.x * 64;
    const int tid = threadIdx.x;
    const int tx = tid & 15, ty = tid >> 4;
    __shared__ float As[64][33];
    __shared__ float Bs[32][65];
    float acc[4][4] = {};
    for (int k0 = 0; k0 < 256; k0 += 32) {
        for (int i = tid; i < 64 * 32; i += 256) {
            int r = i >> 5, c = i & 31;
            As[r][c] = w[(ocB + r) * 256 + k0 + c];
        }
        for (int i = tid; i < 32 * 64; i += 256) {
            int r = i >> 6, c = i & 63;
            Bs[r][c] = O1[((size_t)b * NC + k0 + r) * NHW + nB + c];
        }
        __syncthreads();
        #pragma unroll
        for (int kk = 0; kk < 32; ++kk) {
            float av[4], bv[4];
            #pragma unroll
            for (int i = 0; i < 4; ++i) av[i] = As[ty * 4 + i][kk];
            #pragma unroll
            for (int j = 0; j < 4; ++j) bv[j] = Bs[kk][tx * 4 + j];
            #pragma unroll
            for (int i = 0; i < 4; ++i)
                #pragma unroll
                for (int j = 0; j < 4; ++j)
                    acc[i][j] = fmaf(av[i], bv[j], acc[i][j]);
        }
        __syncthreads();
    }
    #pragma unroll
    for (int i = 0; i < 4; ++i) {
        int oc = ocB + ty * 4 + i;
        float g = bnp[0 * NC + oc], be = bnp[1 * NC + oc];
        float m = bnp[2 * NC + oc], vv = bnp[3 * NC + oc];
        float inv = g * rsqrtf(vv + EPSF);
        float bias = be - m * inv;
        #pragma unroll
        for (int j = 0; j < 4; ++j) {
            int n = nB + tx * 4 + j;
            out[((size_t)b * NC + oc) * NHW + n] = acc[i][j] * inv + bias;
        }
    }
}

extern "C" void kernel_launch(void* const* d_in, const int* in_sizes, int n_in,
                              void* d_out, int out_size, void* d_ws, size_t ws_size,
                              hipStream_t stream) {
    (void)in_sizes; (void)n_in; (void)out_size; (void)ws_size;
    const float* x       = (const float*)d_in[0];
    const float* w_qkv   = (const float*)d_in[1];
    const float* bn_qkv  = (const float*)d_in[2];
    const float* w_cv1   = (const float*)d_in[3];
    const float* bn_cv1  = (const float*)d_in[4];
    const float* w_cv2   = (const float*)d_in[5];
    const float* bn_cv2  = (const float*)d_in[6];
    const float* w_proj  = (const float*)d_in[7];
    const float* bn_proj = (const float*)d_in[8];
    const float* w_pe    = (const float*)d_in[9];
    const float* bn_pe   = (const float*)d_in[10];
    float* out = (float*)d_out;

    float* ws = (float*)d_ws;
    const size_t SZ = (size_t)NB * NC * NHW;           // 8,388,608 floats
    float* Q    = ws;
    float* Kb   = ws + SZ;
    float* Vb   = ws + 2 * SZ;
    float* O1   = Kb;                                  // K dead after k_attn_part
    float* Aa   = ws + 3 * SZ;
    float* AT   = Aa + (size_t)NB * NC * NAG;          // 131072
    float* Pm   = AT + (size_t)NB * NHEAD * NAG * NKD; // 131072
    float* Pl   = Pm + (size_t)NB * NHEAD * NSPLIT * NAG;   // 65536
    float* Pacc = Pl + (size_t)NB * NHEAD * NSPLIT * NAG;   // 65536

    k_qkv<<<dim3(64, 12, NB), 256, 0, stream>>>(x, w_qkv, bn_qkv, Q, Kb, Vb);
    k_gates<<<NB * HDIM, 256, 0, stream>>>(Kb, Vb, w_cv1, bn_cv1, w_cv2, bn_cv2);
    k_pool<<<NB * NC, 64, 0, stream>>>(Q, Aa);
    k_attn_part<<<NB * NHEAD * NSPLIT, 256, 0, stream>>>(Kb, Vb, Aa, Pm, Pl, Pacc);
    k_attn_comb<<<NB * NHEAD, 256, 0, stream>>>(Pm, Pl, Pacc, AT);
    k_qattn<<<dim3(16, NHEAD, NB), 256, 0, stream>>>(Q, Aa, AT, O1);
    k_pe<<<NB * NC, 256, 0, stream>>>(Vb, w_pe, bn_pe, O1);
    k_proj<<<dim3(64, 4, NB), 256, 0, stream>>>(O1, w_proj, bn_proj, out);
}

// Round 4
// 271.120 us; speedup vs baseline: 4.2762x; 2.4419x over previous
//
#include <hip/hip_runtime.h>
#include <hip/hip_bf16.h>

#define NB 8
#define NC 256
#define NHW 4096       // H*W
#define HDIM 64
#define WDIM 64
#define NHEAD 8
#define NKD 32
#define NAG 64
#define NMIP 8
#define NSPLIT 16
#define EPSF 1e-5f
#define FSCALE 0.17677669529663687f  // 32^-0.5
#define SZQ ((size_t)NB * NC * NHW)

typedef __attribute__((ext_vector_type(8))) short bf16x8;
typedef __attribute__((ext_vector_type(4))) float f32x4;

__device__ __forceinline__ unsigned short f2bf(float f) {
    union { float f; unsigned u; } v; v.f = f;
    unsigned r = v.u + 0x7FFF + ((v.u >> 16) & 1);
    return (unsigned short)(r >> 16);
}

// ---------------- K1: qkv = BN(w_qkv @ x), bf16 MFMA ----------------
// grid (32, 6, 8); 256 thr = 4 waves (2x2), 128x128 tile, BK=32
__global__ __launch_bounds__(256) void k_qkv(const float* __restrict__ x,
                                             const float* __restrict__ w,
                                             const float* __restrict__ bnp,
                                             float* __restrict__ Q) {
    const int b   = blockIdx.z;
    const int ocB = blockIdx.y * 128;
    const int nB  = blockIdx.x * 128;
    const int tid = threadIdx.x;
    const int wv  = tid >> 6, lane = tid & 63;
    const int wm = wv >> 1, wn = wv & 1;
    const int lm = lane & 15, lg = lane >> 4;

    __shared__ unsigned short As[128 * 40];   // [m][k] row stride 40
    __shared__ unsigned short Bs[128 * 40];   // [n][k] row stride 40
    __shared__ float inv_s[128], bias_s[128];

    if (tid < 128) {
        int oc = ocB + tid;
        float g = bnp[0 * 768 + oc], be = bnp[1 * 768 + oc];
        float m = bnp[2 * 768 + oc], vv = bnp[3 * 768 + oc];
        float inv = g * rsqrtf(vv + EPSF);
        inv_s[tid] = inv;
        bias_s[tid] = be - m * inv;
    }

    f32x4 acc[4][4];
    #pragma unroll
    for (int i = 0; i < 4; ++i)
        #pragma unroll
        for (int j = 0; j < 4; ++j)
            acc[i][j] = (f32x4){0.f, 0.f, 0.f, 0.f};

    // staging maps
    const int arow = tid >> 1, akh = (tid & 1) * 16;        // A: W[ocB+arow][k0+akh ..+16]
    const int bn_ = tid & 127, bkh = (tid >> 7) * 16;       // B: X[k0+bkh+i][nB+bn_]

    for (int k0 = 0; k0 < 256; k0 += 32) {
        // --- stage A (w is [768][256], k contiguous) ---
        {
            const float* wp = w + (size_t)(ocB + arow) * 256 + k0 + akh;
            float4 f0 = reinterpret_cast<const float4*>(wp)[0];
            float4 f1 = reinterpret_cast<const float4*>(wp)[1];
            float4 f2 = reinterpret_cast<const float4*>(wp)[2];
            float4 f3 = reinterpret_cast<const float4*>(wp)[3];
            union { unsigned short u[16]; bf16x8 v[2]; } pk;
            pk.u[0]=f2bf(f0.x); pk.u[1]=f2bf(f0.y); pk.u[2]=f2bf(f0.z); pk.u[3]=f2bf(f0.w);
            pk.u[4]=f2bf(f1.x); pk.u[5]=f2bf(f1.y); pk.u[6]=f2bf(f1.z); pk.u[7]=f2bf(f1.w);
            pk.u[8]=f2bf(f2.x); pk.u[9]=f2bf(f2.y); pk.u[10]=f2bf(f2.z); pk.u[11]=f2bf(f2.w);
            pk.u[12]=f2bf(f3.x); pk.u[13]=f2bf(f3.y); pk.u[14]=f2bf(f3.z); pk.u[15]=f2bf(f3.w);
            *reinterpret_cast<bf16x8*>(&As[arow * 40 + akh]) = pk.v[0];
            *reinterpret_cast<bf16x8*>(&As[arow * 40 + akh + 8]) = pk.v[1];
        }
        // --- stage B transposed (x rows coalesced, column-slice per thread) ---
        {
            const float* xp = x + ((size_t)b * NC + k0 + bkh) * NHW + nB + bn_;
            float t[16];
            #pragma unroll
            for (int i = 0; i < 16; ++i) t[i] = xp[(size_t)i * NHW];
            union { unsigned short u[16]; bf16x8 v[2]; } pk;
            #pragma unroll
            for (int i = 0; i < 16; ++i) pk.u[i] = f2bf(t[i]);
            *reinterpret_cast<bf16x8*>(&Bs[bn_ * 40 + bkh]) = pk.v[0];
            *reinterpret_cast<bf16x8*>(&Bs[bn_ * 40 + bkh + 8]) = pk.v[1];
        }
        __syncthreads();

        bf16x8 af[4], bfr[4];
        #pragma unroll
        for (int mi = 0; mi < 4; ++mi)
            af[mi] = *reinterpret_cast<const bf16x8*>(&As[(wm * 64 + mi * 16 + lm) * 40 + lg * 8]);
        #pragma unroll
        for (int ni = 0; ni < 4; ++ni)
            bfr[ni] = *reinterpret_cast<const bf16x8*>(&Bs[(wn * 64 + ni * 16 + lm) * 40 + lg * 8]);
        #pragma unroll
        for (int mi = 0; mi < 4; ++mi)
            #pragma unroll
            for (int ni = 0; ni < 4; ++ni)
                acc[mi][ni] = __builtin_amdgcn_mfma_f32_16x16x32_bf16(af[mi], bfr[ni], acc[mi][ni], 0, 0, 0);
        __syncthreads();
    }

    // epilogue: D row = (lane>>4)*4 + r, col = lane&15; route to Q/K/V
    float* dstb = Q + (size_t)(ocB >> 8) * SZQ + ((size_t)b * NC + (ocB & 255)) * NHW + nB;
    #pragma unroll
    for (int mi = 0; mi < 4; ++mi) {
        int lo_base = wm * 64 + mi * 16 + lg * 4;
        #pragma unroll
        for (int r = 0; r < 4; ++r) {
            int lo = lo_base + r;
            float inv = inv_s[lo], bias = bias_s[lo];
            #pragma unroll
            for (int ni = 0; ni < 4; ++ni) {
                int n = wn * 64 + ni * 16 + lm;
                dstb[(size_t)lo * NHW + n] = acc[mi][ni][r] * inv + bias;
            }
        }
    }
}

// ---------------- K2: SE gates per (b,h), fused in-place apply ----------------
__global__ __launch_bounds__(256) void k_gates(float* __restrict__ K,
                                               float* __restrict__ V,
                                               const float* __restrict__ w1,
                                               const float* __restrict__ bn1,
                                               const float* __restrict__ w2,
                                               const float* __restrict__ bn2) {
    const int b = blockIdx.x >> 6;
    const int h = blockIdx.x & 63;
    const int c = threadIdx.x;
    __shared__ float am[NC];
    __shared__ float m1[NMIP];
    for (int pass = 0; pass < 2; ++pass) {
        float* src = pass ? V : K;
        float* row = src + ((size_t)b * NC + c) * NHW + h * WDIM;
        float s = 0.f;
        for (int w = 0; w < WDIM; ++w) s += row[w];
        am[c] = s * (1.0f / WDIM);
        __syncthreads();
        if (c < NMIP) {
            float t = 0.f;
            for (int cc = 0; cc < NC; ++cc) t += w1[c * NC + cc] * am[cc];
            float g = bn1[0 * NMIP + c], be = bn1[1 * NMIP + c];
            float mm = bn1[2 * NMIP + c], vv = bn1[3 * NMIP + c];
            float inv = g * rsqrtf(vv + EPSF);
            m1[c] = t * inv + (be - mm * inv);
        }
        __syncthreads();
        {
            float t = 0.f;
            #pragma unroll
            for (int j = 0; j < NMIP; ++j) t += w2[c * NMIP + j] * m1[j];
            float g = bn2[0 * NC + c], be = bn2[1 * NC + c];
            float mm = bn2[2 * NC + c], vv = bn2[3 * NC + c];
            float inv = g * rsqrtf(vv + EPSF);
            float gate = t * inv + (be - mm * inv);
            for (int w = 0; w < WDIM; ++w) row[w] *= gate;
        }
        __syncthreads();
    }
}

// ---------------- K3: 8x8 block pool of Q -> agent tokens ----------------
__global__ __launch_bounds__(64) void k_pool(const float* __restrict__ Q,
                                             float* __restrict__ A_) {
    const int bc = blockIdx.x;       // b*NC + c
    const int ag = threadIdx.x;      // 0..63
    const int ph = ag >> 3, pw = ag & 7;
    const float* src = Q + (size_t)bc * NHW;
    float s = 0.f;
    #pragma unroll
    for (int i = 0; i < 8; ++i)
        #pragma unroll
        for (int j = 0; j < 8; ++j)
            s += src[(ph * 8 + i) * WDIM + pw * 8 + j];
    A_[(size_t)bc * NAG + ag] = s * (1.0f / 64.0f);
}

// ---------------- K4a: agent attn partials (split-N flash) ----------------
__global__ __launch_bounds__(256) void k_attn_part(const float* __restrict__ K,
                                                   const float* __restrict__ V,
                                                   const float* __restrict__ A_,
                                                   float* __restrict__ Pm,
                                                   float* __restrict__ Pl,
                                                   float* __restrict__ Pacc) {
    const int bh = blockIdx.x >> 4;
    const int ns = blockIdx.x & (NSPLIT - 1);
    const int b = bh >> 3, h = bh & 7;
    const int tid = threadIdx.x;
    const int agq = tid >> 4;
    const int jq  = tid & 15;
    __shared__ float a_s[32][64];
    __shared__ float kt[32][64];
    __shared__ float vt_t[64][34];
    __shared__ float p_s[64][68];

    for (int i = tid; i < 32 * 64; i += 256) {
        int d = i >> 6, ag = i & 63;
        a_s[d][ag] = A_[((size_t)(b * NC + h * NKD + d)) * NAG + ag] * FSCALE;
    }

    float mrow[4], lrow[4], acc[4][2];
    #pragma unroll
    for (int i = 0; i < 4; ++i) {
        mrow[i] = -1e30f; lrow[i] = 0.f; acc[i][0] = 0.f; acc[i][1] = 0.f;
    }

    const int ncols = NHW / NSPLIT;                 // 256
    const float* Kp = K + (size_t)(b * NC + h * NKD) * NHW + ns * ncols;
    const float* Vp = V + (size_t)(b * NC + h * NKD) * NHW + ns * ncols;

    for (int nt = 0; nt < ncols / 64; ++nt) {       // 4 tiles
        for (int i = tid; i < 32 * 64; i += 256) {
            int r = i >> 6, cc = i & 63;
            kt[r][cc]   = Kp[(size_t)r * NHW + nt * 64 + cc];
            vt_t[cc][r] = Vp[(size_t)r * NHW + nt * 64 + cc];
        }
        __syncthreads();

        float s[4][4] = {};
        #pragma unroll
        for (int kk = 0; kk < 32; ++kk) {
            float4 av = *reinterpret_cast<const float4*>(&a_s[kk][agq * 4]);
            float4 kv = *reinterpret_cast<const float4*>(&kt[kk][jq * 4]);
            float aa[4] = {av.x, av.y, av.z, av.w};
            float bb[4] = {kv.x, kv.y, kv.z, kv.w};
            #pragma unroll
            for (int i = 0; i < 4; ++i)
                #pragma unroll
                for (int jj = 0; jj < 4; ++jj)
                    s[i][jj] = fmaf(aa[i], bb[jj], s[i][jj]);
        }
        float f[4];
        #pragma unroll
        for (int i = 0; i < 4; ++i) {
            float pm = fmaxf(fmaxf(s[i][0], s[i][1]), fmaxf(s[i][2], s[i][3]));
            pm = fmaxf(pm, __shfl_xor(pm, 1));
            pm = fmaxf(pm, __shfl_xor(pm, 2));
            pm = fmaxf(pm, __shfl_xor(pm, 4));
            pm = fmaxf(pm, __shfl_xor(pm, 8));
            float mnew = fmaxf(mrow[i], pm);
            f[i] = __expf(mrow[i] - mnew);
            mrow[i] = mnew;
            float ps = 0.f;
            #pragma unroll
            for (int jj = 0; jj < 4; ++jj) {
                float p = __expf(s[i][jj] - mnew);
                p_s[jq * 4 + jj][agq * 4 + i] = p;
                ps += p;
            }
            ps += __shfl_xor(ps, 1);
            ps += __shfl_xor(ps, 2);
            ps += __shfl_xor(ps, 4);
            ps += __shfl_xor(ps, 8);
            lrow[i] = lrow[i] * f[i] + ps;
            acc[i][0] *= f[i];
            acc[i][1] *= f[i];
        }
        __syncthreads();

        #pragma unroll 4
        for (int j = 0; j < 64; ++j) {
            float4 pv = *reinterpret_cast<const float4*>(&p_s[j][agq * 4]);
            float2 vv = *reinterpret_cast<const float2*>(&vt_t[j][jq * 2]);
            float pp[4] = {pv.x, pv.y, pv.z, pv.w};
            #pragma unroll
            for (int i = 0; i < 4; ++i) {
                acc[i][0] = fmaf(pp[i], vv.x, acc[i][0]);
                acc[i][1] = fmaf(pp[i], vv.y, acc[i][1]);
            }
        }
        __syncthreads();
    }

    const size_t pbase = (size_t)(bh * NSPLIT + ns) * NAG;
    #pragma unroll
    for (int i = 0; i < 4; ++i) {
        int ag = agq * 4 + i;
        #pragma unroll
        for (int dd = 0; dd < 2; ++dd)
            Pacc[(pbase + ag) * NKD + jq * 2 + dd] = acc[i][dd];
        if (jq == 0) {
            Pm[pbase + ag] = mrow[i];
            Pl[pbase + ag] = lrow[i];
        }
    }
}

// ---------------- K4b: combine partials ----------------
__global__ __launch_bounds__(256) void k_attn_comb(const float* __restrict__ Pm,
                                                   const float* __restrict__ Pl,
                                                   const float* __restrict__ Pacc,
                                                   float* __restrict__ AT) {
    const int bh = blockIdx.x;
    const int tid = threadIdx.x;
    const int ag = tid >> 2, jg = tid & 3;
    float m = -1e30f;
    #pragma unroll
    for (int ns = 0; ns < NSPLIT; ++ns)
        m = fmaxf(m, Pm[(size_t)(bh * NSPLIT + ns) * NAG + ag]);
    float l = 0.f;
    float acc[8] = {};
    for (int ns = 0; ns < NSPLIT; ++ns) {
        size_t pb = (size_t)(bh * NSPLIT + ns) * NAG + ag;
        float f = __expf(Pm[pb] - m);
        l += Pl[pb] * f;
        const float* pp = Pacc + pb * NKD + jg * 8;
        #pragma unroll
        for (int i = 0; i < 8; ++i) acc[i] += pp[i] * f;
    }
    float linv = 1.0f / l;
    #pragma unroll
    for (int i = 0; i < 8; ++i)
        AT[((size_t)bh * NAG + ag) * NKD + jg * 8 + i] = acc[i] * linv;
}

// ---------------- K5: out1 = softmax_ag(q^T a) @ attn ----------------
__global__ __launch_bounds__(256) void k_qattn(const float* __restrict__ Q,
                                               const float* __restrict__ A_,
                                               const float* __restrict__ AT,
                                               float* __restrict__ O1) {
    const int b = blockIdx.z, h = blockIdx.y;
    const int n = blockIdx.x * 256 + threadIdx.x;
    __shared__ float a_s[NKD][NAG + 1];
    __shared__ float at_s[NAG][NKD];
    for (int i = threadIdx.x; i < NKD * NAG; i += 256) {
        int d = i >> 6, ag = i & 63;
        a_s[d][ag] = A_[((size_t)(b * NC + h * NKD + d)) * NAG + ag] * FSCALE;
    }
    for (int i = threadIdx.x; i < NAG * NKD; i += 256)
        at_s[i >> 5][i & 31] = AT[(size_t)(b * NHEAD + h) * NAG * NKD + i];
    __syncthreads();

    float q[32];
    const float* qp = Q + ((size_t)b * NC + h * NKD) * NHW + n;
    #pragma unroll
    for (int d = 0; d < 32; ++d) q[d] = qp[(size_t)d * NHW];

    float s[64];
    float mx = -1e30f;
    #pragma unroll
    for (int ag = 0; ag < 64; ++ag) {
        float t = 0.f;
        #pragma unroll
        for (int d = 0; d < 32; ++d) t = fmaf(q[d], a_s[d][ag], t);
        s[ag] = t;
        mx = fmaxf(mx, t);
    }
    float out[32];
    #pragma unroll
    for (int d = 0; d < 32; ++d) out[d] = 0.f;
    float l = 0.f;
    #pragma unroll
    for (int ag = 0; ag < 64; ++ag) {
        float p = __expf(s[ag] - mx);
        l += p;
        #pragma unroll
        for (int d = 0; d < 32; ++d) out[d] = fmaf(p, at_s[ag][d], out[d]);
    }
    float rl = 1.0f / l;
    float* op = O1 + ((size_t)b * NC + h * NKD) * NHW + n;
    #pragma unroll
    for (int d = 0; d < 32; ++d) op[(size_t)d * NHW] = out[d] * rl;
}

// ---------------- K6: O1 += BN(depthwise 3x3 conv of V) ----------------
__global__ __launch_bounds__(256) void k_pe(const float* __restrict__ V,
                                            const float* __restrict__ wpe,
                                            const float* __restrict__ bnp,
                                            float* __restrict__ O1) {
    const int bc = blockIdx.x;
    const int c = bc & (NC - 1);
    float wreg[9];
    #pragma unroll
    for (int i = 0; i < 9; ++i) wreg[i] = wpe[c * 9 + i];
    float g = bnp[0 * NC + c], be = bnp[1 * NC + c];
    float m = bnp[2 * NC + c], vv = bnp[3 * NC + c];
    float inv = g * rsqrtf(vv + EPSF);
    float bias = be - m * inv;
    const float* src = V + (size_t)bc * NHW;
    float* dst = O1 + (size_t)bc * NHW;
    for (int idx = threadIdx.x; idx < NHW; idx += 256) {
        int h = idx >> 6, w = idx & 63;
        float s = 0.f;
        #pragma unroll
        for (int kh = 0; kh < 3; ++kh) {
            int hh = h + kh - 1;
            if (hh < 0 || hh >= HDIM) continue;
            #pragma unroll
            for (int kw = 0; kw < 3; ++kw) {
                int ww = w + kw - 1;
                if (ww < 0 || ww >= WDIM) continue;
                s = fmaf(wreg[kh * 3 + kw], src[hh * WDIM + ww], s);
            }
        }
        dst[idx] += s * inv + bias;
    }
}

// ---------------- K7: out = BN(w_proj @ O1), bf16 MFMA ----------------
// grid (32, 2, 8)
__global__ __launch_bounds__(256) void k_proj(const float* __restrict__ O1,
                                              const float* __restrict__ w,
                                              const float* __restrict__ bnp,
                                              float* __restrict__ out) {
    const int b   = blockIdx.z;
    const int ocB = blockIdx.y * 128;
    const int nB  = blockIdx.x * 128;
    const int tid = threadIdx.x;
    const int wv  = tid >> 6, lane = tid & 63;
    const int wm = wv >> 1, wn = wv & 1;
    const int lm = lane & 15, lg = lane >> 4;

    __shared__ unsigned short As[128 * 40];
    __shared__ unsigned short Bs[128 * 40];
    __shared__ float inv_s[128], bias_s[128];

    if (tid < 128) {
        int oc = ocB + tid;
        float g = bnp[0 * NC + oc], be = bnp[1 * NC + oc];
        float m = bnp[2 * NC + oc], vv = bnp[3 * NC + oc];
        float inv = g * rsqrtf(vv + EPSF);
        inv_s[tid] = inv;
        bias_s[tid] = be - m * inv;
    }

    f32x4 acc[4][4];
    #pragma unroll
    for (int i = 0; i < 4; ++i)
        #pragma unroll
        for (int j = 0; j < 4; ++j)
            acc[i][j] = (f32x4){0.f, 0.f, 0.f, 0.f};

    const int arow = tid >> 1, akh = (tid & 1) * 16;
    const int bn_ = tid & 127, bkh = (tid >> 7) * 16;

    for (int k0 = 0; k0 < 256; k0 += 32) {
        {
            const float* wp = w + (size_t)(ocB + arow) * 256 + k0 + akh;
            float4 f0 = reinterpret_cast<const float4*>(wp)[0];
            float4 f1 = reinterpret_cast<const float4*>(wp)[1];
            float4 f2 = reinterpret_cast<const float4*>(wp)[2];
            float4 f3 = reinterpret_cast<const float4*>(wp)[3];
            union { unsigned short u[16]; bf16x8 v[2]; } pk;
            pk.u[0]=f2bf(f0.x); pk.u[1]=f2bf(f0.y); pk.u[2]=f2bf(f0.z); pk.u[3]=f2bf(f0.w);
            pk.u[4]=f2bf(f1.x); pk.u[5]=f2bf(f1.y); pk.u[6]=f2bf(f1.z); pk.u[7]=f2bf(f1.w);
            pk.u[8]=f2bf(f2.x); pk.u[9]=f2bf(f2.y); pk.u[10]=f2bf(f2.z); pk.u[11]=f2bf(f2.w);
            pk.u[12]=f2bf(f3.x); pk.u[13]=f2bf(f3.y); pk.u[14]=f2bf(f3.z); pk.u[15]=f2bf(f3.w);
            *reinterpret_cast<bf16x8*>(&As[arow * 40 + akh]) = pk.v[0];
            *reinterpret_cast<bf16x8*>(&As[arow * 40 + akh + 8]) = pk.v[1];
        }
        {
            const float* xp = O1 + ((size_t)b * NC + k0 + bkh) * NHW + nB + bn_;
            float t[16];
            #pragma unroll
            for (int i = 0; i < 16; ++i) t[i] = xp[(size_t)i * NHW];
            union { unsigned short u[16]; bf16x8 v[2]; } pk;
            #pragma unroll
            for (int i = 0; i < 16; ++i) pk.u[i] = f2bf(t[i]);
            *reinterpret_cast<bf16x8*>(&Bs[bn_ * 40 + bkh]) = pk.v[0];
            *reinterpret_cast<bf16x8*>(&Bs[bn_ * 40 + bkh + 8]) = pk.v[1];
        }
        __syncthreads();

        bf16x8 af[4], bfr[4];
        #pragma unroll
        for (int mi = 0; mi < 4; ++mi)
            af[mi] = *reinterpret_cast<const bf16x8*>(&As[(wm * 64 + mi * 16 + lm) * 40 + lg * 8]);
        #pragma unroll
        for (int ni = 0; ni < 4; ++ni)
            bfr[ni] = *reinterpret_cast<const bf16x8*>(&Bs[(wn * 64 + ni * 16 + lm) * 40 + lg * 8]);
        #pragma unroll
        for (int mi = 0; mi < 4; ++mi)
            #pragma unroll
            for (int ni = 0; ni < 4; ++ni)
                acc[mi][ni] = __builtin_amdgcn_mfma_f32_16x16x32_bf16(af[mi], bfr[ni], acc[mi][ni], 0, 0, 0);
        __syncthreads();
    }

    float* dstb = out + ((size_t)b * NC + ocB) * NHW + nB;
    #pragma unroll
    for (int mi = 0; mi < 4; ++mi) {
        int lo_base = wm * 64 + mi * 16 + lg * 4;
        #pragma unroll
        for (int r = 0; r < 4; ++r) {
            int lo = lo_base + r;
            float inv = inv_s[lo], bias = bias_s[lo];
            #pragma unroll
            for (int ni = 0; ni < 4; ++ni) {
                int n = wn * 64 + ni * 16 + lm;
                dstb[(size_t)lo * NHW + n] = acc[mi][ni][r] * inv + bias;
            }
        }
    }
}

extern "C" void kernel_launch(void* const* d_in, const int* in_sizes, int n_in,
                              void* d_out, int out_size, void* d_ws, size_t ws_size,
                              hipStream_t stream) {
    (void)in_sizes; (void)n_in; (void)out_size; (void)ws_size;
    const float* x       = (const float*)d_in[0];
    const float* w_qkv   = (const float*)d_in[1];
    const float* bn_qkv  = (const float*)d_in[2];
    const float* w_cv1   = (const float*)d_in[3];
    const float* bn_cv1  = (const float*)d_in[4];
    const float* w_cv2   = (const float*)d_in[5];
    const float* bn_cv2  = (const float*)d_in[6];
    const float* w_proj  = (const float*)d_in[7];
    const float* bn_proj = (const float*)d_in[8];
    const float* w_pe    = (const float*)d_in[9];
    const float* bn_pe   = (const float*)d_in[10];
    float* out = (float*)d_out;

    float* ws = (float*)d_ws;
    float* Q    = ws;
    float* Kb   = ws + SZQ;
    float* Vb   = ws + 2 * SZQ;
    float* O1   = Kb;                                  // K dead after k_attn_part
    float* Aa   = ws + 3 * SZQ;
    float* AT   = Aa + (size_t)NB * NC * NAG;          // 131072
    float* Pm   = AT + (size_t)NB * NHEAD * NAG * NKD; // 131072
    float* Pl   = Pm + (size_t)NB * NHEAD * NSPLIT * NAG;   // 65536
    float* Pacc = Pl + (size_t)NB * NHEAD * NSPLIT * NAG;   // 65536

    k_qkv<<<dim3(32, 6, NB), 256, 0, stream>>>(x, w_qkv, bn_qkv, Q);
    k_gates<<<NB * HDIM, 256, 0, stream>>>(Kb, Vb, w_cv1, bn_cv1, w_cv2, bn_cv2);
    k_pool<<<NB * NC, 64, 0, stream>>>(Q, Aa);
    k_attn_part<<<NB * NHEAD * NSPLIT, 256, 0, stream>>>(Kb, Vb, Aa, Pm, Pl, Pacc);
    k_attn_comb<<<NB * NHEAD, 256, 0, stream>>>(Pm, Pl, Pacc, AT);
    k_qattn<<<dim3(16, NHEAD, NB), 256, 0, stream>>>(Q, Aa, AT, O1);
    k_pe<<<NB * NC, 256, 0, stream>>>(Vb, w_pe, bn_pe, O1);
    k_proj<<<dim3(32, 2, NB), 256, 0, stream>>>(O1, w_proj, bn_proj, out);
}

// Round 5
// 232.077 us; speedup vs baseline: 4.9956x; 1.1682x over previous
//
#include <hip/hip_runtime.h>
#include <hip/hip_bf16.h>

#define NB 8
#define NC 256
#define NHW 4096       // H*W
#define HDIM 64
#define WDIM 64
#define NHEAD 8
#define NKD 32
#define NAG 64
#define NMIP 8
#define NSPLIT 16
#define EPSF 1e-5f
#define FSCALE 0.17677669529663687f  // 32^-0.5
#define SZQ ((size_t)NB * NC * NHW)

typedef __attribute__((ext_vector_type(8))) short bf16x8;
typedef __attribute__((ext_vector_type(4))) float f32x4;

__device__ __forceinline__ unsigned short f2bf(float f) {
    union { float f; unsigned u; } v; v.f = f;
    unsigned r = v.u + 0x7FFF + ((v.u >> 16) & 1);
    return (unsigned short)(r >> 16);
}

// ---------------- K1: qkv = BN(w_qkv @ x), bf16 MFMA ----------------
// grid (32, 6, 8); 256 thr = 4 waves (2x2), 128x128 tile, BK=32
__global__ __launch_bounds__(256) void k_qkv(const float* __restrict__ x,
                                             const float* __restrict__ w,
                                             const float* __restrict__ bnp,
                                             float* __restrict__ Q) {
    const int b   = blockIdx.z;
    const int ocB = blockIdx.y * 128;
    const int nB  = blockIdx.x * 128;
    const int tid = threadIdx.x;
    const int wv  = tid >> 6, lane = tid & 63;
    const int wm = wv >> 1, wn = wv & 1;
    const int lm = lane & 15, lg = lane >> 4;

    __shared__ unsigned short As[128 * 40];   // [m][k] row stride 40
    __shared__ unsigned short Bs[128 * 40];   // [n][k] row stride 40
    __shared__ float inv_s[128], bias_s[128];

    if (tid < 128) {
        int oc = ocB + tid;
        float g = bnp[0 * 768 + oc], be = bnp[1 * 768 + oc];
        float m = bnp[2 * 768 + oc], vv = bnp[3 * 768 + oc];
        float inv = g * rsqrtf(vv + EPSF);
        inv_s[tid] = inv;
        bias_s[tid] = be - m * inv;
    }

    f32x4 acc[4][4];
    #pragma unroll
    for (int i = 0; i < 4; ++i)
        #pragma unroll
        for (int j = 0; j < 4; ++j)
            acc[i][j] = (f32x4){0.f, 0.f, 0.f, 0.f};

    const int arow = tid >> 1, akh = (tid & 1) * 16;        // A: W[ocB+arow][k0+akh ..+16]
    const int bn_ = tid & 127, bkh = (tid >> 7) * 16;       // B: X[k0+bkh+i][nB+bn_]

    for (int k0 = 0; k0 < 256; k0 += 32) {
        {
            const float* wp = w + (size_t)(ocB + arow) * 256 + k0 + akh;
            float4 f0 = reinterpret_cast<const float4*>(wp)[0];
            float4 f1 = reinterpret_cast<const float4*>(wp)[1];
            float4 f2 = reinterpret_cast<const float4*>(wp)[2];
            float4 f3 = reinterpret_cast<const float4*>(wp)[3];
            union { unsigned short u[16]; bf16x8 v[2]; } pk;
            pk.u[0]=f2bf(f0.x); pk.u[1]=f2bf(f0.y); pk.u[2]=f2bf(f0.z); pk.u[3]=f2bf(f0.w);
            pk.u[4]=f2bf(f1.x); pk.u[5]=f2bf(f1.y); pk.u[6]=f2bf(f1.z); pk.u[7]=f2bf(f1.w);
            pk.u[8]=f2bf(f2.x); pk.u[9]=f2bf(f2.y); pk.u[10]=f2bf(f2.z); pk.u[11]=f2bf(f2.w);
            pk.u[12]=f2bf(f3.x); pk.u[13]=f2bf(f3.y); pk.u[14]=f2bf(f3.z); pk.u[15]=f2bf(f3.w);
            *reinterpret_cast<bf16x8*>(&As[arow * 40 + akh]) = pk.v[0];
            *reinterpret_cast<bf16x8*>(&As[arow * 40 + akh + 8]) = pk.v[1];
        }
        {
            const float* xp = x + ((size_t)b * NC + k0 + bkh) * NHW + nB + bn_;
            float t[16];
            #pragma unroll
            for (int i = 0; i < 16; ++i) t[i] = xp[(size_t)i * NHW];
            union { unsigned short u[16]; bf16x8 v[2]; } pk;
            #pragma unroll
            for (int i = 0; i < 16; ++i) pk.u[i] = f2bf(t[i]);
            *reinterpret_cast<bf16x8*>(&Bs[bn_ * 40 + bkh]) = pk.v[0];
            *reinterpret_cast<bf16x8*>(&Bs[bn_ * 40 + bkh + 8]) = pk.v[1];
        }
        __syncthreads();

        bf16x8 af[4], bfr[4];
        #pragma unroll
        for (int mi = 0; mi < 4; ++mi)
            af[mi] = *reinterpret_cast<const bf16x8*>(&As[(wm * 64 + mi * 16 + lm) * 40 + lg * 8]);
        #pragma unroll
        for (int ni = 0; ni < 4; ++ni)
            bfr[ni] = *reinterpret_cast<const bf16x8*>(&Bs[(wn * 64 + ni * 16 + lm) * 40 + lg * 8]);
        #pragma unroll
        for (int mi = 0; mi < 4; ++mi)
            #pragma unroll
            for (int ni = 0; ni < 4; ++ni)
                acc[mi][ni] = __builtin_amdgcn_mfma_f32_16x16x32_bf16(af[mi], bfr[ni], acc[mi][ni], 0, 0, 0);
        __syncthreads();
    }

    float* dstb = Q + (size_t)(ocB >> 8) * SZQ + ((size_t)b * NC + (ocB & 255)) * NHW + nB;
    #pragma unroll
    for (int mi = 0; mi < 4; ++mi) {
        int lo_base = wm * 64 + mi * 16 + lg * 4;
        #pragma unroll
        for (int r = 0; r < 4; ++r) {
            int lo = lo_base + r;
            float inv = inv_s[lo], bias = bias_s[lo];
            #pragma unroll
            for (int ni = 0; ni < 4; ++ni) {
                int n = wn * 64 + ni * 16 + lm;
                dstb[(size_t)lo * NHW + n] = acc[mi][ni][r] * inv + bias;
            }
        }
    }
}

// ---------------- K2: SE gates per (b,h), fused in-place apply ----------------
__global__ __launch_bounds__(256) void k_gates(float* __restrict__ K,
                                               float* __restrict__ V,
                                               const float* __restrict__ w1,
                                               const float* __restrict__ bn1,
                                               const float* __restrict__ w2,
                                               const float* __restrict__ bn2) {
    const int b = blockIdx.x >> 6;
    const int h = blockIdx.x & 63;
    const int c = threadIdx.x;
    __shared__ float am[NC];
    __shared__ float m1[NMIP];
    for (int pass = 0; pass < 2; ++pass) {
        float* src = pass ? V : K;
        float* row = src + ((size_t)b * NC + c) * NHW + h * WDIM;
        float s = 0.f;
        for (int w = 0; w < WDIM; ++w) s += row[w];
        am[c] = s * (1.0f / WDIM);
        __syncthreads();
        if (c < NMIP) {
            float t = 0.f;
            for (int cc = 0; cc < NC; ++cc) t += w1[c * NC + cc] * am[cc];
            float g = bn1[0 * NMIP + c], be = bn1[1 * NMIP + c];
            float mm = bn1[2 * NMIP + c], vv = bn1[3 * NMIP + c];
            float inv = g * rsqrtf(vv + EPSF);
            m1[c] = t * inv + (be - mm * inv);
        }
        __syncthreads();
        {
            float t = 0.f;
            #pragma unroll
            for (int j = 0; j < NMIP; ++j) t += w2[c * NMIP + j] * m1[j];
            float g = bn2[0 * NC + c], be = bn2[1 * NC + c];
            float mm = bn2[2 * NC + c], vv = bn2[3 * NC + c];
            float inv = g * rsqrtf(vv + EPSF);
            float gate = t * inv + (be - mm * inv);
            for (int w = 0; w < WDIM; ++w) row[w] *= gate;
        }
        __syncthreads();
    }
}

// ---------------- K3: 8x8 block pool of Q -> agent tokens ----------------
__global__ __launch_bounds__(64) void k_pool(const float* __restrict__ Q,
                                             float* __restrict__ A_) {
    const int bc = blockIdx.x;       // b*NC + c
    const int ag = threadIdx.x;      // 0..63
    const int ph = ag >> 3, pw = ag & 7;
    const float* src = Q + (size_t)bc * NHW;
    float s = 0.f;
    #pragma unroll
    for (int i = 0; i < 8; ++i)
        #pragma unroll
        for (int j = 0; j < 8; ++j)
            s += src[(ph * 8 + i) * WDIM + pw * 8 + j];
    A_[(size_t)bc * NAG + ag] = s * (1.0f / 64.0f);
}

// ---------------- K4a: agent attn partials (split-N flash) ----------------
__global__ __launch_bounds__(256) void k_attn_part(const float* __restrict__ K,
                                                   const float* __restrict__ V,
                                                   const float* __restrict__ A_,
                                                   float* __restrict__ Pm,
                                                   float* __restrict__ Pl,
                                                   float* __restrict__ Pacc) {
    const int bh = blockIdx.x >> 4;
    const int ns = blockIdx.x & (NSPLIT - 1);
    const int b = bh >> 3, h = bh & 7;
    const int tid = threadIdx.x;
    const int agq = tid >> 4;
    const int jq  = tid & 15;
    __shared__ float a_s[32][64];
    __shared__ float kt[32][64];
    __shared__ float vt_t[64][34];
    __shared__ float p_s[64][68];

    for (int i = tid; i < 32 * 64; i += 256) {
        int d = i >> 6, ag = i & 63;
        a_s[d][ag] = A_[((size_t)(b * NC + h * NKD + d)) * NAG + ag] * FSCALE;
    }

    float mrow[4], lrow[4], acc[4][2];
    #pragma unroll
    for (int i = 0; i < 4; ++i) {
        mrow[i] = -1e30f; lrow[i] = 0.f; acc[i][0] = 0.f; acc[i][1] = 0.f;
    }

    const int ncols = NHW / NSPLIT;                 // 256
    const float* Kp = K + (size_t)(b * NC + h * NKD) * NHW + ns * ncols;
    const float* Vp = V + (size_t)(b * NC + h * NKD) * NHW + ns * ncols;

    for (int nt = 0; nt < ncols / 64; ++nt) {       // 4 tiles
        for (int i = tid; i < 32 * 64; i += 256) {
            int r = i >> 6, cc = i & 63;
            kt[r][cc]   = Kp[(size_t)r * NHW + nt * 64 + cc];
            vt_t[cc][r] = Vp[(size_t)r * NHW + nt * 64 + cc];
        }
        __syncthreads();

        float s[4][4] = {};
        #pragma unroll
        for (int kk = 0; kk < 32; ++kk) {
            float4 av = *reinterpret_cast<const float4*>(&a_s[kk][agq * 4]);
            float4 kv = *reinterpret_cast<const float4*>(&kt[kk][jq * 4]);
            float aa[4] = {av.x, av.y, av.z, av.w};
            float bb[4] = {kv.x, kv.y, kv.z, kv.w};
            #pragma unroll
            for (int i = 0; i < 4; ++i)
                #pragma unroll
                for (int jj = 0; jj < 4; ++jj)
                    s[i][jj] = fmaf(aa[i], bb[jj], s[i][jj]);
        }
        float f[4];
        #pragma unroll
        for (int i = 0; i < 4; ++i) {
            float pm = fmaxf(fmaxf(s[i][0], s[i][1]), fmaxf(s[i][2], s[i][3]));
            pm = fmaxf(pm, __shfl_xor(pm, 1));
            pm = fmaxf(pm, __shfl_xor(pm, 2));
            pm = fmaxf(pm, __shfl_xor(pm, 4));
            pm = fmaxf(pm, __shfl_xor(pm, 8));
            float mnew = fmaxf(mrow[i], pm);
            f[i] = __expf(mrow[i] - mnew);
            mrow[i] = mnew;
            float ps = 0.f;
            #pragma unroll
            for (int jj = 0; jj < 4; ++jj) {
                float p = __expf(s[i][jj] - mnew);
                p_s[jq * 4 + jj][agq * 4 + i] = p;
                ps += p;
            }
            ps += __shfl_xor(ps, 1);
            ps += __shfl_xor(ps, 2);
            ps += __shfl_xor(ps, 4);
            ps += __shfl_xor(ps, 8);
            lrow[i] = lrow[i] * f[i] + ps;
            acc[i][0] *= f[i];
            acc[i][1] *= f[i];
        }
        __syncthreads();

        #pragma unroll 4
        for (int j = 0; j < 64; ++j) {
            float4 pv = *reinterpret_cast<const float4*>(&p_s[j][agq * 4]);
            float2 vv = *reinterpret_cast<const float2*>(&vt_t[j][jq * 2]);
            float pp[4] = {pv.x, pv.y, pv.z, pv.w};
            #pragma unroll
            for (int i = 0; i < 4; ++i) {
                acc[i][0] = fmaf(pp[i], vv.x, acc[i][0]);
                acc[i][1] = fmaf(pp[i], vv.y, acc[i][1]);
            }
        }
        __syncthreads();
    }

    const size_t pbase = (size_t)(bh * NSPLIT + ns) * NAG;
    #pragma unroll
    for (int i = 0; i < 4; ++i) {
        int ag = agq * 4 + i;
        #pragma unroll
        for (int dd = 0; dd < 2; ++dd)
            Pacc[(pbase + ag) * NKD + jq * 2 + dd] = acc[i][dd];
        if (jq == 0) {
            Pm[pbase + ag] = mrow[i];
            Pl[pbase + ag] = lrow[i];
        }
    }
}

// ---------------- K4b: combine partials ----------------
__global__ __launch_bounds__(256) void k_attn_comb(const float* __restrict__ Pm,
                                                   const float* __restrict__ Pl,
                                                   const float* __restrict__ Pacc,
                                                   float* __restrict__ AT) {
    const int bh = blockIdx.x;
    const int tid = threadIdx.x;
    const int ag = tid >> 2, jg = tid & 3;
    float m = -1e30f;
    #pragma unroll
    for (int ns = 0; ns < NSPLIT; ++ns)
        m = fmaxf(m, Pm[(size_t)(bh * NSPLIT + ns) * NAG + ag]);
    float l = 0.f;
    float acc[8] = {};
    for (int ns = 0; ns < NSPLIT; ++ns) {
        size_t pb = (size_t)(bh * NSPLIT + ns) * NAG + ag;
        float f = __expf(Pm[pb] - m);
        l += Pl[pb] * f;
        const float* pp = Pacc + pb * NKD + jg * 8;
        #pragma unroll
        for (int i = 0; i < 8; ++i) acc[i] += pp[i] * f;
    }
    float linv = 1.0f / l;
    #pragma unroll
    for (int i = 0; i < 8; ++i)
        AT[((size_t)bh * NAG + ag) * NKD + jg * 8 + i] = acc[i] * linv;
}

// ---------------- K5: out1 = softmax_ag(q^T a) @ attn, bf16 MFMA ----------------
// grid (32 ntiles, 64 bh); 256 thr = 4 waves; 128 n-rows per block
__global__ __launch_bounds__(256) void k_qattn(const float* __restrict__ Q,
                                               const float* __restrict__ A_,
                                               const float* __restrict__ AT,
                                               float* __restrict__ O1) {
    const int bh = blockIdx.y;
    const int b = bh >> 3, h = bh & 7;
    const int n0 = blockIdx.x * 128;
    const int tid = threadIdx.x;
    const int wv = tid >> 6, lane = tid & 63;
    const int lm = lane & 15, lg = lane >> 4;

    __shared__ unsigned short Qs[128][40];    // [n][d]
    __shared__ unsigned short Ags[64][40];    // [ag][d]  (pre-scaled)
    __shared__ unsigned short ATs[32][72];    // [d][ag]
    __shared__ unsigned short Ps[128][72];    // [n][ag]

    const float* Qbase = Q + ((size_t)b * NC + h * NKD) * NHW;

    // stage Q tile transposed: thread t: d = t>>3, nblk = (t&7)*16
    {
        int d = tid >> 3, nb_ = (tid & 7) * 16;
        const float* qp = Qbase + (size_t)d * NHW + n0 + nb_;
        float4 v0 = reinterpret_cast<const float4*>(qp)[0];
        float4 v1 = reinterpret_cast<const float4*>(qp)[1];
        float4 v2 = reinterpret_cast<const float4*>(qp)[2];
        float4 v3 = reinterpret_cast<const float4*>(qp)[3];
        float t[16] = {v0.x,v0.y,v0.z,v0.w, v1.x,v1.y,v1.z,v1.w,
                       v2.x,v2.y,v2.z,v2.w, v3.x,v3.y,v3.z,v3.w};
        #pragma unroll
        for (int i = 0; i < 16; ++i) Qs[nb_ + i][d] = f2bf(t[i]);
    }
    // stage A (scaled) transposed: t<128: d = t>>2, ag0 = (t&3)*16
    if (tid < 128) {
        int d = tid >> 2, ag0 = (tid & 3) * 16;
        const float* ap = A_ + ((size_t)(b * NC + h * NKD + d)) * NAG + ag0;
        #pragma unroll
        for (int i = 0; i < 16; ++i) Ags[ag0 + i][d] = f2bf(ap[i] * FSCALE);
    }
    // stage AT transposed: t<128: ag = t>>1, d0 = (t&1)*16
    if (tid < 128) {
        int ag = tid >> 1, d0 = (tid & 1) * 16;
        const float* atp = AT + ((size_t)bh * NAG + ag) * NKD + d0;
        #pragma unroll
        for (int i = 0; i < 16; ++i) ATs[d0 + i][ag] = f2bf(atp[i]);
    }
    __syncthreads();

    // S = Q^T A : rows = wv*32 + mi*16, cols = ag (4 frags), k = d = 32
    f32x4 s[2][4];
    #pragma unroll
    for (int mi = 0; mi < 2; ++mi)
        #pragma unroll
        for (int ni = 0; ni < 4; ++ni)
            s[mi][ni] = (f32x4){0.f, 0.f, 0.f, 0.f};
    {
        bf16x8 qa[2], ab[4];
        #pragma unroll
        for (int mi = 0; mi < 2; ++mi)
            qa[mi] = *reinterpret_cast<const bf16x8*>(&Qs[wv * 32 + mi * 16 + lm][lg * 8]);
        #pragma unroll
        for (int ni = 0; ni < 4; ++ni)
            ab[ni] = *reinterpret_cast<const bf16x8*>(&Ags[ni * 16 + lm][lg * 8]);
        #pragma unroll
        for (int mi = 0; mi < 2; ++mi)
            #pragma unroll
            for (int ni = 0; ni < 4; ++ni)
                s[mi][ni] = __builtin_amdgcn_mfma_f32_16x16x32_bf16(qa[mi], ab[ni], s[mi][ni], 0, 0, 0);
    }

    // softmax over ag (cols): group of 16 lanes (same lg) holds cols 0..15 of same 4 rows
    float lsum[2][4];
    #pragma unroll
    for (int mi = 0; mi < 2; ++mi) {
        #pragma unroll
        for (int r = 0; r < 4; ++r) {
            float mx = fmaxf(fmaxf(s[mi][0][r], s[mi][1][r]), fmaxf(s[mi][2][r], s[mi][3][r]));
            mx = fmaxf(mx, __shfl_xor(mx, 1));
            mx = fmaxf(mx, __shfl_xor(mx, 2));
            mx = fmaxf(mx, __shfl_xor(mx, 4));
            mx = fmaxf(mx, __shfl_xor(mx, 8));
            int nrow = wv * 32 + mi * 16 + lg * 4 + r;
            float ls = 0.f;
            #pragma unroll
            for (int ni = 0; ni < 4; ++ni) {
                float p = __expf(s[mi][ni][r] - mx);
                ls += p;
                Ps[nrow][ni * 16 + lm] = f2bf(p);
            }
            ls += __shfl_xor(ls, 1);
            ls += __shfl_xor(ls, 2);
            ls += __shfl_xor(ls, 4);
            ls += __shfl_xor(ls, 8);
            lsum[mi][r] = ls;
        }
    }
    __syncthreads();

    // O = P @ AT : rows same, cols = d (2 frags), k = ag = 64 (2 steps)
    f32x4 o[2][2];
    #pragma unroll
    for (int mi = 0; mi < 2; ++mi)
        #pragma unroll
        for (int ni = 0; ni < 2; ++ni)
            o[mi][ni] = (f32x4){0.f, 0.f, 0.f, 0.f};
    #pragma unroll
    for (int kk = 0; kk < 2; ++kk) {
        bf16x8 pa[2], vb[2];
        #pragma unroll
        for (int mi = 0; mi < 2; ++mi)
            pa[mi] = *reinterpret_cast<const bf16x8*>(&Ps[wv * 32 + mi * 16 + lm][kk * 32 + lg * 8]);
        #pragma unroll
        for (int ni = 0; ni < 2; ++ni)
            vb[ni] = *reinterpret_cast<const bf16x8*>(&ATs[ni * 16 + lm][kk * 32 + lg * 8]);
        #pragma unroll
        for (int mi = 0; mi < 2; ++mi)
            #pragma unroll
            for (int ni = 0; ni < 2; ++ni)
                o[mi][ni] = __builtin_amdgcn_mfma_f32_16x16x32_bf16(pa[mi], vb[ni], o[mi][ni], 0, 0, 0);
    }

    float* obase = O1 + ((size_t)b * NC + h * NKD) * NHW + n0;
    #pragma unroll
    for (int mi = 0; mi < 2; ++mi) {
        #pragma unroll
        for (int r = 0; r < 4; ++r) {
            float rl = 1.0f / lsum[mi][r];
            int n = wv * 32 + mi * 16 + lg * 4 + r;
            #pragma unroll
            for (int ni = 0; ni < 2; ++ni) {
                int d = ni * 16 + lm;
                obase[(size_t)d * NHW + n] = o[mi][ni][r] * rl;
            }
        }
    }
}

// ---------------- K6: O1 += BN(depthwise 3x3 conv of V) ----------------
__global__ __launch_bounds__(256) void k_pe(const float* __restrict__ V,
                                            const float* __restrict__ wpe,
                                            const float* __restrict__ bnp,
                                            float* __restrict__ O1) {
    const int bc = blockIdx.x;
    const int c = bc & (NC - 1);
    float wreg[9];
    #pragma unroll
    for (int i = 0; i < 9; ++i) wreg[i] = wpe[c * 9 + i];
    float g = bnp[0 * NC + c], be = bnp[1 * NC + c];
    float m = bnp[2 * NC + c], vv = bnp[3 * NC + c];
    float inv = g * rsqrtf(vv + EPSF);
    float bias = be - m * inv;
    const float* src = V + (size_t)bc * NHW;
    float* dst = O1 + (size_t)bc * NHW;
    for (int idx = threadIdx.x; idx < NHW; idx += 256) {
        int h = idx >> 6, w = idx & 63;
        float s = 0.f;
        #pragma unroll
        for (int kh = 0; kh < 3; ++kh) {
            int hh = h + kh - 1;
            if (hh < 0 || hh >= HDIM) continue;
            #pragma unroll
            for (int kw = 0; kw < 3; ++kw) {
                int ww = w + kw - 1;
                if (ww < 0 || ww >= WDIM) continue;
                s = fmaf(wreg[kh * 3 + kw], src[hh * WDIM + ww], s);
            }
        }
        dst[idx] += s * inv + bias;
    }
}

// ---------------- K7: out = BN(w_proj @ O1), bf16 MFMA ----------------
__global__ __launch_bounds__(256) void k_proj(const float* __restrict__ O1,
                                              const float* __restrict__ w,
                                              const float* __restrict__ bnp,
                                              float* __restrict__ out) {
    const int b   = blockIdx.z;
    const int ocB = blockIdx.y * 128;
    const int nB  = blockIdx.x * 128;
    const int tid = threadIdx.x;
    const int wv  = tid >> 6, lane = tid & 63;
    const int wm = wv >> 1, wn = wv & 1;
    const int lm = lane & 15, lg = lane >> 4;

    __shared__ unsigned short As[128 * 40];
    __shared__ unsigned short Bs[128 * 40];
    __shared__ float inv_s[128], bias_s[128];

    if (tid < 128) {
        int oc = ocB + tid;
        float g = bnp[0 * NC + oc], be = bnp[1 * NC + oc];
        float m = bnp[2 * NC + oc], vv = bnp[3 * NC + oc];
        float inv = g * rsqrtf(vv + EPSF);
        inv_s[tid] = inv;
        bias_s[tid] = be - m * inv;
    }

    f32x4 acc[4][4];
    #pragma unroll
    for (int i = 0; i < 4; ++i)
        #pragma unroll
        for (int j = 0; j < 4; ++j)
            acc[i][j] = (f32x4){0.f, 0.f, 0.f, 0.f};

    const int arow = tid >> 1, akh = (tid & 1) * 16;
    const int bn_ = tid & 127, bkh = (tid >> 7) * 16;

    for (int k0 = 0; k0 < 256; k0 += 32) {
        {
            const float* wp = w + (size_t)(ocB + arow) * 256 + k0 + akh;
            float4 f0 = reinterpret_cast<const float4*>(wp)[0];
            float4 f1 = reinterpret_cast<const float4*>(wp)[1];
            float4 f2 = reinterpret_cast<const float4*>(wp)[2];
            float4 f3 = reinterpret_cast<const float4*>(wp)[3];
            union { unsigned short u[16]; bf16x8 v[2]; } pk;
            pk.u[0]=f2bf(f0.x); pk.u[1]=f2bf(f0.y); pk.u[2]=f2bf(f0.z); pk.u[3]=f2bf(f0.w);
            pk.u[4]=f2bf(f1.x); pk.u[5]=f2bf(f1.y); pk.u[6]=f2bf(f1.z); pk.u[7]=f2bf(f1.w);
            pk.u[8]=f2bf(f2.x); pk.u[9]=f2bf(f2.y); pk.u[10]=f2bf(f2.z); pk.u[11]=f2bf(f2.w);
            pk.u[12]=f2bf(f3.x); pk.u[13]=f2bf(f3.y); pk.u[14]=f2bf(f3.z); pk.u[15]=f2bf(f3.w);
            *reinterpret_cast<bf16x8*>(&As[arow * 40 + akh]) = pk.v[0];
            *reinterpret_cast<bf16x8*>(&As[arow * 40 + akh + 8]) = pk.v[1];
        }
        {
            const float* xp = O1 + ((size_t)b * NC + k0 + bkh) * NHW + nB + bn_;
            float t[16];
            #pragma unroll
            for (int i = 0; i < 16; ++i) t[i] = xp[(size_t)i * NHW];
            union { unsigned short u[16]; bf16x8 v[2]; } pk;
            #pragma unroll
            for (int i = 0; i < 16; ++i) pk.u[i] = f2bf(t[i]);
            *reinterpret_cast<bf16x8*>(&Bs[bn_ * 40 + bkh]) = pk.v[0];
            *reinterpret_cast<bf16x8*>(&Bs[bn_ * 40 + bkh + 8]) = pk.v[1];
        }
        __syncthreads();

        bf16x8 af[4], bfr[4];
        #pragma unroll
        for (int mi = 0; mi < 4; ++mi)
            af[mi] = *reinterpret_cast<const bf16x8*>(&As[(wm * 64 + mi * 16 + lm) * 40 + lg * 8]);
        #pragma unroll
        for (int ni = 0; ni < 4; ++ni)
            bfr[ni] = *reinterpret_cast<const bf16x8*>(&Bs[(wn * 64 + ni * 16 + lm) * 40 + lg * 8]);
        #pragma unroll
        for (int mi = 0; mi < 4; ++mi)
            #pragma unroll
            for (int ni = 0; ni < 4; ++ni)
                acc[mi][ni] = __builtin_amdgcn_mfma_f32_16x16x32_bf16(af[mi], bfr[ni], acc[mi][ni], 0, 0, 0);
        __syncthreads();
    }

    float* dstb = out + ((size_t)b * NC + ocB) * NHW + nB;
    #pragma unroll
    for (int mi = 0; mi < 4; ++mi) {
        int lo_base = wm * 64 + mi * 16 + lg * 4;
        #pragma unroll
        for (int r = 0; r < 4; ++r) {
            int lo = lo_base + r;
            float inv = inv_s[lo], bias = bias_s[lo];
            #pragma unroll
            for (int ni = 0; ni < 4; ++ni) {
                int n = wn * 64 + ni * 16 + lm;
                dstb[(size_t)lo * NHW + n] = acc[mi][ni][r] * inv + bias;
            }
        }
    }
}

extern "C" void kernel_launch(void* const* d_in, const int* in_sizes, int n_in,
                              void* d_out, int out_size, void* d_ws, size_t ws_size,
                              hipStream_t stream) {
    (void)in_sizes; (void)n_in; (void)out_size; (void)ws_size;
    const float* x       = (const float*)d_in[0];
    const float* w_qkv   = (const float*)d_in[1];
    const float* bn_qkv  = (const float*)d_in[2];
    const float* w_cv1   = (const float*)d_in[3];
    const float* bn_cv1  = (const float*)d_in[4];
    const float* w_cv2   = (const float*)d_in[5];
    const float* bn_cv2  = (const float*)d_in[6];
    const float* w_proj  = (const float*)d_in[7];
    const float* bn_proj = (const float*)d_in[8];
    const float* w_pe    = (const float*)d_in[9];
    const float* bn_pe   = (const float*)d_in[10];
    float* out = (float*)d_out;

    float* ws = (float*)d_ws;
    float* Q    = ws;
    float* Kb   = ws + SZQ;
    float* Vb   = ws + 2 * SZQ;
    float* O1   = Kb;                                  // K dead after k_attn_part
    float* Aa   = ws + 3 * SZQ;
    float* AT   = Aa + (size_t)NB * NC * NAG;          // 131072
    float* Pm   = AT + (size_t)NB * NHEAD * NAG * NKD; // 131072
    float* Pl   = Pm + (size_t)NB * NHEAD * NSPLIT * NAG;   // 65536
    float* Pacc = Pl + (size_t)NB * NHEAD * NSPLIT * NAG;   // 65536

    k_qkv<<<dim3(32, 6, NB), 256, 0, stream>>>(x, w_qkv, bn_qkv, Q);
    k_gates<<<NB * HDIM, 256, 0, stream>>>(Kb, Vb, w_cv1, bn_cv1, w_cv2, bn_cv2);
    k_pool<<<NB * NC, 64, 0, stream>>>(Q, Aa);
    k_attn_part<<<NB * NHEAD * NSPLIT, 256, 0, stream>>>(Kb, Vb, Aa, Pm, Pl, Pacc);
    k_attn_comb<<<NB * NHEAD, 256, 0, stream>>>(Pm, Pl, Pacc, AT);
    k_qattn<<<dim3(32, 64), 256, 0, stream>>>(Q, Aa, AT, O1);
    k_pe<<<NB * NC, 256, 0, stream>>>(Vb, w_pe, bn_pe, O1);
    k_proj<<<dim3(32, 2, NB), 256, 0, stream>>>(O1, w_proj, bn_proj, out);
}

// Round 6
// 202.912 us; speedup vs baseline: 5.7136x; 1.1437x over previous
//
#include <hip/hip_runtime.h>
#include <hip/hip_bf16.h>

#define NB 8
#define NC 256
#define NHW 4096       // H*W
#define HDIM 64
#define WDIM 64
#define NHEAD 8
#define NKD 32
#define NAG 64
#define NMIP 8
#define NSPLIT 16
#define EPSF 1e-5f
#define FSCALE 0.17677669529663687f  // 32^-0.5
#define SZQ ((size_t)NB * NC * NHW)

typedef __attribute__((ext_vector_type(8))) short bf16x8;
typedef __attribute__((ext_vector_type(4))) float f32x4;

__device__ __forceinline__ unsigned short f2bf(float f) {
    union { float f; unsigned u; } v; v.f = f;
    unsigned r = v.u + 0x7FFF + ((v.u >> 16) & 1);
    return (unsigned short)(r >> 16);
}

// ---------------- K1: qkv = BN(w_qkv @ x), bf16 MFMA ----------------
// grid (32, 6, 8); 256 thr = 4 waves (2x2), 128x128 tile, BK=32
__global__ __launch_bounds__(256) void k_qkv(const float* __restrict__ x,
                                             const float* __restrict__ w,
                                             const float* __restrict__ bnp,
                                             float* __restrict__ Q) {
    const int b   = blockIdx.z;
    const int ocB = blockIdx.y * 128;
    const int nB  = blockIdx.x * 128;
    const int tid = threadIdx.x;
    const int wv  = tid >> 6, lane = tid & 63;
    const int wm = wv >> 1, wn = wv & 1;
    const int lm = lane & 15, lg = lane >> 4;

    __shared__ unsigned short As[128 * 40];   // [m][k] row stride 40
    __shared__ unsigned short Bs[128 * 40];   // [n][k] row stride 40
    __shared__ float inv_s[128], bias_s[128];

    if (tid < 128) {
        int oc = ocB + tid;
        float g = bnp[0 * 768 + oc], be = bnp[1 * 768 + oc];
        float m = bnp[2 * 768 + oc], vv = bnp[3 * 768 + oc];
        float inv = g * rsqrtf(vv + EPSF);
        inv_s[tid] = inv;
        bias_s[tid] = be - m * inv;
    }

    f32x4 acc[4][4];
    #pragma unroll
    for (int i = 0; i < 4; ++i)
        #pragma unroll
        for (int j = 0; j < 4; ++j)
            acc[i][j] = (f32x4){0.f, 0.f, 0.f, 0.f};

    const int arow = tid >> 1, akh = (tid & 1) * 16;        // A: W[ocB+arow][k0+akh ..+16]
    const int bn_ = tid & 127, bkh = (tid >> 7) * 16;       // B: X[k0+bkh+i][nB+bn_]

    for (int k0 = 0; k0 < 256; k0 += 32) {
        {
            const float* wp = w + (size_t)(ocB + arow) * 256 + k0 + akh;
            float4 f0 = reinterpret_cast<const float4*>(wp)[0];
            float4 f1 = reinterpret_cast<const float4*>(wp)[1];
            float4 f2 = reinterpret_cast<const float4*>(wp)[2];
            float4 f3 = reinterpret_cast<const float4*>(wp)[3];
            union { unsigned short u[16]; bf16x8 v[2]; } pk;
            pk.u[0]=f2bf(f0.x); pk.u[1]=f2bf(f0.y); pk.u[2]=f2bf(f0.z); pk.u[3]=f2bf(f0.w);
            pk.u[4]=f2bf(f1.x); pk.u[5]=f2bf(f1.y); pk.u[6]=f2bf(f1.z); pk.u[7]=f2bf(f1.w);
            pk.u[8]=f2bf(f2.x); pk.u[9]=f2bf(f2.y); pk.u[10]=f2bf(f2.z); pk.u[11]=f2bf(f2.w);
            pk.u[12]=f2bf(f3.x); pk.u[13]=f2bf(f3.y); pk.u[14]=f2bf(f3.z); pk.u[15]=f2bf(f3.w);
            *reinterpret_cast<bf16x8*>(&As[arow * 40 + akh]) = pk.v[0];
            *reinterpret_cast<bf16x8*>(&As[arow * 40 + akh + 8]) = pk.v[1];
        }
        {
            const float* xp = x + ((size_t)b * NC + k0 + bkh) * NHW + nB + bn_;
            float t[16];
            #pragma unroll
            for (int i = 0; i < 16; ++i) t[i] = xp[(size_t)i * NHW];
            union { unsigned short u[16]; bf16x8 v[2]; } pk;
            #pragma unroll
            for (int i = 0; i < 16; ++i) pk.u[i] = f2bf(t[i]);
            *reinterpret_cast<bf16x8*>(&Bs[bn_ * 40 + bkh]) = pk.v[0];
            *reinterpret_cast<bf16x8*>(&Bs[bn_ * 40 + bkh + 8]) = pk.v[1];
        }
        __syncthreads();

        bf16x8 af[4], bfr[4];
        #pragma unroll
        for (int mi = 0; mi < 4; ++mi)
            af[mi] = *reinterpret_cast<const bf16x8*>(&As[(wm * 64 + mi * 16 + lm) * 40 + lg * 8]);
        #pragma unroll
        for (int ni = 0; ni < 4; ++ni)
            bfr[ni] = *reinterpret_cast<const bf16x8*>(&Bs[(wn * 64 + ni * 16 + lm) * 40 + lg * 8]);
        #pragma unroll
        for (int mi = 0; mi < 4; ++mi)
            #pragma unroll
            for (int ni = 0; ni < 4; ++ni)
                acc[mi][ni] = __builtin_amdgcn_mfma_f32_16x16x32_bf16(af[mi], bfr[ni], acc[mi][ni], 0, 0, 0);
        __syncthreads();
    }

    float* dstb = Q + (size_t)(ocB >> 8) * SZQ + ((size_t)b * NC + (ocB & 255)) * NHW + nB;
    #pragma unroll
    for (int mi = 0; mi < 4; ++mi) {
        int lo_base = wm * 64 + mi * 16 + lg * 4;
        #pragma unroll
        for (int r = 0; r < 4; ++r) {
            int lo = lo_base + r;
            float inv = inv_s[lo], bias = bias_s[lo];
            #pragma unroll
            for (int ni = 0; ni < 4; ++ni) {
                int n = wn * 64 + ni * 16 + lm;
                dstb[(size_t)lo * NHW + n] = acc[mi][ni][r] * inv + bias;
            }
        }
    }
}

// ---------------- K2: SE gates per (b,h), fused in-place apply ----------------
__global__ __launch_bounds__(256) void k_gates(float* __restrict__ K,
                                               float* __restrict__ V,
                                               const float* __restrict__ w1,
                                               const float* __restrict__ bn1,
                                               const float* __restrict__ w2,
                                               const float* __restrict__ bn2) {
    const int b = blockIdx.x >> 6;
    const int h = blockIdx.x & 63;
    const int c = threadIdx.x;
    __shared__ float am[NC];
    __shared__ float m1[NMIP];
    for (int pass = 0; pass < 2; ++pass) {
        float* src = pass ? V : K;
        float* row = src + ((size_t)b * NC + c) * NHW + h * WDIM;
        float s = 0.f;
        for (int w = 0; w < WDIM; ++w) s += row[w];
        am[c] = s * (1.0f / WDIM);
        __syncthreads();
        if (c < NMIP) {
            float t = 0.f;
            for (int cc = 0; cc < NC; ++cc) t += w1[c * NC + cc] * am[cc];
            float g = bn1[0 * NMIP + c], be = bn1[1 * NMIP + c];
            float mm = bn1[2 * NMIP + c], vv = bn1[3 * NMIP + c];
            float inv = g * rsqrtf(vv + EPSF);
            m1[c] = t * inv + (be - mm * inv);
        }
        __syncthreads();
        {
            float t = 0.f;
            #pragma unroll
            for (int j = 0; j < NMIP; ++j) t += w2[c * NMIP + j] * m1[j];
            float g = bn2[0 * NC + c], be = bn2[1 * NC + c];
            float mm = bn2[2 * NC + c], vv = bn2[3 * NC + c];
            float inv = g * rsqrtf(vv + EPSF);
            float gate = t * inv + (be - mm * inv);
            for (int w = 0; w < WDIM; ++w) row[w] *= gate;
        }
        __syncthreads();
    }
}

// ---------------- K3: 8x8 block pool of Q -> agent tokens ----------------
__global__ __launch_bounds__(64) void k_pool(const float* __restrict__ Q,
                                             float* __restrict__ A_) {
    const int bc = blockIdx.x;       // b*NC + c
    const int ag = threadIdx.x;      // 0..63
    const int ph = ag >> 3, pw = ag & 7;
    const float* src = Q + (size_t)bc * NHW;
    float s = 0.f;
    #pragma unroll
    for (int i = 0; i < 8; ++i)
        #pragma unroll
        for (int j = 0; j < 8; ++j)
            s += src[(ph * 8 + i) * WDIM + pw * 8 + j];
    A_[(size_t)bc * NAG + ag] = s * (1.0f / 64.0f);
}

// ---------------- K4a: agent attn partials (split-N flash), bf16 MFMA ----------------
// grid = NB*NHEAD*NSPLIT; 256 thr = 4 waves; wave wv owns ag rows wv*16..+16
__global__ __launch_bounds__(256) void k_attn_part(const float* __restrict__ K,
                                                   const float* __restrict__ V,
                                                   const float* __restrict__ A_,
                                                   float* __restrict__ Pm,
                                                   float* __restrict__ Pl,
                                                   float* __restrict__ Pacc) {
    const int bh = blockIdx.x >> 4;
    const int ns = blockIdx.x & (NSPLIT - 1);
    const int b = bh >> 3, h = bh & 7;
    const int tid = threadIdx.x;
    const int wv = tid >> 6, lane = tid & 63;
    const int lm = lane & 15, lg = lane >> 4;

    __shared__ unsigned short a_s[64 * 40];   // [ag][d]
    __shared__ unsigned short kt_s[64 * 40];  // [col][d]
    __shared__ unsigned short vt_s[32 * 72];  // [dd][col]
    __shared__ unsigned short Ps[64 * 72];    // [ag][col]

    // stage a_s (pre-scaled), once: thread: d = tid>>3, ag0 = (tid&7)*8
    {
        int d = tid >> 3, ag0 = (tid & 7) * 8;
        const float* ap = A_ + ((size_t)(b * NC + h * NKD + d)) * NAG + ag0;
        float4 v0 = reinterpret_cast<const float4*>(ap)[0];
        float4 v1 = reinterpret_cast<const float4*>(ap)[1];
        float t8[8] = {v0.x, v0.y, v0.z, v0.w, v1.x, v1.y, v1.z, v1.w};
        #pragma unroll
        for (int i = 0; i < 8; ++i)
            a_s[(ag0 + i) * 40 + d] = f2bf(t8[i] * FSCALE);
    }

    float mrow[4], lrow[4];
    f32x4 acc[2];
    #pragma unroll
    for (int r = 0; r < 4; ++r) { mrow[r] = -1e30f; lrow[r] = 0.f; }
    acc[0] = (f32x4){0.f, 0.f, 0.f, 0.f};
    acc[1] = (f32x4){0.f, 0.f, 0.f, 0.f};

    const int colbase = ns * (NHW / NSPLIT);
    const float* Kp = K + (size_t)(b * NC + h * NKD) * NHW + colbase;
    const float* Vp = V + (size_t)(b * NC + h * NKD) * NHW + colbase;
    __syncthreads();

    for (int nt = 0; nt < 4; ++nt) {
        // stage K tile transposed: thread: d = tid>>3, c0 = tid&7, cols c0+8i
        {
            int d = tid >> 3, c0 = tid & 7;
            const float* kp = Kp + (size_t)d * NHW + nt * 64 + c0;
            #pragma unroll
            for (int i = 0; i < 8; ++i)
                kt_s[(c0 + 8 * i) * 40 + d] = f2bf(kp[8 * i]);
        }
        // stage V tile straight: thread: d = tid>>3, c0 = (tid&7)*8
        {
            int d = tid >> 3, c0 = (tid & 7) * 8;
            const float* vp = Vp + (size_t)d * NHW + nt * 64 + c0;
            float4 v0 = reinterpret_cast<const float4*>(vp)[0];
            float4 v1 = reinterpret_cast<const float4*>(vp)[1];
            float t8[8] = {v0.x, v0.y, v0.z, v0.w, v1.x, v1.y, v1.z, v1.w};
            union { unsigned short u[8]; bf16x8 v; } pk;
            #pragma unroll
            for (int i = 0; i < 8; ++i) pk.u[i] = f2bf(t8[i]);
            *reinterpret_cast<bf16x8*>(&vt_s[d * 72 + c0]) = pk.v;
        }
        __syncthreads();

        // S = a^T k : wave rows wv*16..+16, cols 64 (4 frags), k=32
        f32x4 s[4];
        {
            bf16x8 af = *reinterpret_cast<const bf16x8*>(&a_s[(wv * 16 + lm) * 40 + lg * 8]);
            #pragma unroll
            for (int ni = 0; ni < 4; ++ni) {
                bf16x8 kf = *reinterpret_cast<const bf16x8*>(&kt_s[(ni * 16 + lm) * 40 + lg * 8]);
                s[ni] = __builtin_amdgcn_mfma_f32_16x16x32_bf16(
                    af, kf, (f32x4){0.f, 0.f, 0.f, 0.f}, 0, 0, 0);
            }
        }

        // online softmax per row (row = wv*16 + lg*4 + r, cols spread over lm & ni)
        float fsc[4];
        #pragma unroll
        for (int r = 0; r < 4; ++r) {
            float mx = fmaxf(fmaxf(s[0][r], s[1][r]), fmaxf(s[2][r], s[3][r]));
            mx = fmaxf(mx, __shfl_xor(mx, 1));
            mx = fmaxf(mx, __shfl_xor(mx, 2));
            mx = fmaxf(mx, __shfl_xor(mx, 4));
            mx = fmaxf(mx, __shfl_xor(mx, 8));
            float mnew = fmaxf(mrow[r], mx);
            fsc[r] = __expf(mrow[r] - mnew);
            mrow[r] = mnew;
            int agrow = wv * 16 + lg * 4 + r;
            float ps = 0.f;
            #pragma unroll
            for (int ni = 0; ni < 4; ++ni) {
                float p = __expf(s[ni][r] - mnew);
                Ps[agrow * 72 + ni * 16 + lm] = f2bf(p);
                ps += p;
            }
            ps += __shfl_xor(ps, 1);
            ps += __shfl_xor(ps, 2);
            ps += __shfl_xor(ps, 4);
            ps += __shfl_xor(ps, 8);
            lrow[r] = lrow[r] * fsc[r] + ps;
        }
        #pragma unroll
        for (int ni = 0; ni < 2; ++ni)
            #pragma unroll
            for (int r = 0; r < 4; ++r)
                acc[ni][r] *= fsc[r];
        __syncthreads();

        // PV: rows = ag (same), cols = dd (2 frags), k = 64 cols (2 steps)
        #pragma unroll
        for (int kk = 0; kk < 2; ++kk) {
            bf16x8 pa = *reinterpret_cast<const bf16x8*>(&Ps[(wv * 16 + lm) * 72 + kk * 32 + lg * 8]);
            #pragma unroll
            for (int ni = 0; ni < 2; ++ni) {
                bf16x8 vb = *reinterpret_cast<const bf16x8*>(&vt_s[(ni * 16 + lm) * 72 + kk * 32 + lg * 8]);
                acc[ni] = __builtin_amdgcn_mfma_f32_16x16x32_bf16(pa, vb, acc[ni], 0, 0, 0);
            }
        }
        __syncthreads();
    }

    const size_t pbase = (size_t)(bh * NSPLIT + ns) * NAG;
    #pragma unroll
    for (int r = 0; r < 4; ++r) {
        int ag = wv * 16 + lg * 4 + r;
        #pragma unroll
        for (int ni = 0; ni < 2; ++ni)
            Pacc[(pbase + ag) * NKD + ni * 16 + lm] = acc[ni][r];
        if (lm == 0) {
            Pm[pbase + ag] = mrow[r];
            Pl[pbase + ag] = lrow[r];
        }
    }
}

// ---------------- K4b: combine partials ----------------
__global__ __launch_bounds__(256) void k_attn_comb(const float* __restrict__ Pm,
                                                   const float* __restrict__ Pl,
                                                   const float* __restrict__ Pacc,
                                                   float* __restrict__ AT) {
    const int bh = blockIdx.x;
    const int tid = threadIdx.x;
    const int ag = tid >> 2, jg = tid & 3;
    float m = -1e30f;
    #pragma unroll
    for (int ns = 0; ns < NSPLIT; ++ns)
        m = fmaxf(m, Pm[(size_t)(bh * NSPLIT + ns) * NAG + ag]);
    float l = 0.f;
    float acc[8] = {};
    for (int ns = 0; ns < NSPLIT; ++ns) {
        size_t pb = (size_t)(bh * NSPLIT + ns) * NAG + ag;
        float f = __expf(Pm[pb] - m);
        l += Pl[pb] * f;
        const float* pp = Pacc + pb * NKD + jg * 8;
        #pragma unroll
        for (int i = 0; i < 8; ++i) acc[i] += pp[i] * f;
    }
    float linv = 1.0f / l;
    #pragma unroll
    for (int i = 0; i < 8; ++i)
        AT[((size_t)bh * NAG + ag) * NKD + jg * 8 + i] = acc[i] * linv;
}

// ---------------- K5: out1 = softmax_ag(q^T a) @ attn, bf16 MFMA ----------------
// grid (32 ntiles, 64 bh); 256 thr = 4 waves; 128 n-rows per block
__global__ __launch_bounds__(256) void k_qattn(const float* __restrict__ Q,
                                               const float* __restrict__ A_,
                                               const float* __restrict__ AT,
                                               float* __restrict__ O1) {
    const int bh = blockIdx.y;
    const int b = bh >> 3, h = bh & 7;
    const int n0 = blockIdx.x * 128;
    const int tid = threadIdx.x;
    const int wv = tid >> 6, lane = tid & 63;
    const int lm = lane & 15, lg = lane >> 4;

    __shared__ unsigned short Qs[128][40];    // [n][d]
    __shared__ unsigned short Ags[64][40];    // [ag][d]  (pre-scaled)
    __shared__ unsigned short ATs[32][72];    // [d][ag]
    __shared__ unsigned short Ps[128][72];    // [n][ag]

    const float* Qbase = Q + ((size_t)b * NC + h * NKD) * NHW;

    {
        int d = tid >> 3, nb_ = (tid & 7) * 16;
        const float* qp = Qbase + (size_t)d * NHW + n0 + nb_;
        float4 v0 = reinterpret_cast<const float4*>(qp)[0];
        float4 v1 = reinterpret_cast<const float4*>(qp)[1];
        float4 v2 = reinterpret_cast<const float4*>(qp)[2];
        float4 v3 = reinterpret_cast<const float4*>(qp)[3];
        float t[16] = {v0.x,v0.y,v0.z,v0.w, v1.x,v1.y,v1.z,v1.w,
                       v2.x,v2.y,v2.z,v2.w, v3.x,v3.y,v3.z,v3.w};
        #pragma unroll
        for (int i = 0; i < 16; ++i) Qs[nb_ + i][d] = f2bf(t[i]);
    }
    if (tid < 128) {
        int d = tid >> 2, ag0 = (tid & 3) * 16;
        const float* ap = A_ + ((size_t)(b * NC + h * NKD + d)) * NAG + ag0;
        #pragma unroll
        for (int i = 0; i < 16; ++i) Ags[ag0 + i][d] = f2bf(ap[i] * FSCALE);
    }
    if (tid < 128) {
        int ag = tid >> 1, d0 = (tid & 1) * 16;
        const float* atp = AT + ((size_t)bh * NAG + ag) * NKD + d0;
        #pragma unroll
        for (int i = 0; i < 16; ++i) ATs[d0 + i][ag] = f2bf(atp[i]);
    }
    __syncthreads();

    f32x4 s[2][4];
    #pragma unroll
    for (int mi = 0; mi < 2; ++mi)
        #pragma unroll
        for (int ni = 0; ni < 4; ++ni)
            s[mi][ni] = (f32x4){0.f, 0.f, 0.f, 0.f};
    {
        bf16x8 qa[2], ab[4];
        #pragma unroll
        for (int mi = 0; mi < 2; ++mi)
            qa[mi] = *reinterpret_cast<const bf16x8*>(&Qs[wv * 32 + mi * 16 + lm][lg * 8]);
        #pragma unroll
        for (int ni = 0; ni < 4; ++ni)
            ab[ni] = *reinterpret_cast<const bf16x8*>(&Ags[ni * 16 + lm][lg * 8]);
        #pragma unroll
        for (int mi = 0; mi < 2; ++mi)
            #pragma unroll
            for (int ni = 0; ni < 4; ++ni)
                s[mi][ni] = __builtin_amdgcn_mfma_f32_16x16x32_bf16(qa[mi], ab[ni], s[mi][ni], 0, 0, 0);
    }

    float lsum[2][4];
    #pragma unroll
    for (int mi = 0; mi < 2; ++mi) {
        #pragma unroll
        for (int r = 0; r < 4; ++r) {
            float mx = fmaxf(fmaxf(s[mi][0][r], s[mi][1][r]), fmaxf(s[mi][2][r], s[mi][3][r]));
            mx = fmaxf(mx, __shfl_xor(mx, 1));
            mx = fmaxf(mx, __shfl_xor(mx, 2));
            mx = fmaxf(mx, __shfl_xor(mx, 4));
            mx = fmaxf(mx, __shfl_xor(mx, 8));
            int nrow = wv * 32 + mi * 16 + lg * 4 + r;
            float ls = 0.f;
            #pragma unroll
            for (int ni = 0; ni < 4; ++ni) {
                float p = __expf(s[mi][ni][r] - mx);
                ls += p;
                Ps[nrow][ni * 16 + lm] = f2bf(p);
            }
            ls += __shfl_xor(ls, 1);
            ls += __shfl_xor(ls, 2);
            ls += __shfl_xor(ls, 4);
            ls += __shfl_xor(ls, 8);
            lsum[mi][r] = ls;
        }
    }
    __syncthreads();

    f32x4 o[2][2];
    #pragma unroll
    for (int mi = 0; mi < 2; ++mi)
        #pragma unroll
        for (int ni = 0; ni < 2; ++ni)
            o[mi][ni] = (f32x4){0.f, 0.f, 0.f, 0.f};
    #pragma unroll
    for (int kk = 0; kk < 2; ++kk) {
        bf16x8 pa[2], vb[2];
        #pragma unroll
        for (int mi = 0; mi < 2; ++mi)
            pa[mi] = *reinterpret_cast<const bf16x8*>(&Ps[wv * 32 + mi * 16 + lm][kk * 32 + lg * 8]);
        #pragma unroll
        for (int ni = 0; ni < 2; ++ni)
            vb[ni] = *reinterpret_cast<const bf16x8*>(&ATs[ni * 16 + lm][kk * 32 + lg * 8]);
        #pragma unroll
        for (int mi = 0; mi < 2; ++mi)
            #pragma unroll
            for (int ni = 0; ni < 2; ++ni)
                o[mi][ni] = __builtin_amdgcn_mfma_f32_16x16x32_bf16(pa[mi], vb[ni], o[mi][ni], 0, 0, 0);
    }

    float* obase = O1 + ((size_t)b * NC + h * NKD) * NHW + n0;
    #pragma unroll
    for (int mi = 0; mi < 2; ++mi) {
        #pragma unroll
        for (int r = 0; r < 4; ++r) {
            float rl = 1.0f / lsum[mi][r];
            int n = wv * 32 + mi * 16 + lg * 4 + r;
            #pragma unroll
            for (int ni = 0; ni < 2; ++ni) {
                int d = ni * 16 + lm;
                obase[(size_t)d * NHW + n] = o[mi][ni][r] * rl;
            }
        }
    }
}

// ---------------- K6: O1 += BN(depthwise 3x3 conv of V) ----------------
__global__ __launch_bounds__(256) void k_pe(const float* __restrict__ V,
                                            const float* __restrict__ wpe,
                                            const float* __restrict__ bnp,
                                            float* __restrict__ O1) {
    const int bc = blockIdx.x;
    const int c = bc & (NC - 1);
    float wreg[9];
    #pragma unroll
    for (int i = 0; i < 9; ++i) wreg[i] = wpe[c * 9 + i];
    float g = bnp[0 * NC + c], be = bnp[1 * NC + c];
    float m = bnp[2 * NC + c], vv = bnp[3 * NC + c];
    float inv = g * rsqrtf(vv + EPSF);
    float bias = be - m * inv;
    const float* src = V + (size_t)bc * NHW;
    float* dst = O1 + (size_t)bc * NHW;
    for (int idx = threadIdx.x; idx < NHW; idx += 256) {
        int h = idx >> 6, w = idx & 63;
        float s = 0.f;
        #pragma unroll
        for (int kh = 0; kh < 3; ++kh) {
            int hh = h + kh - 1;
            if (hh < 0 || hh >= HDIM) continue;
            #pragma unroll
            for (int kw = 0; kw < 3; ++kw) {
                int ww = w + kw - 1;
                if (ww < 0 || ww >= WDIM) continue;
                s = fmaf(wreg[kh * 3 + kw], src[hh * WDIM + ww], s);
            }
        }
        dst[idx] += s * inv + bias;
    }
}

// ---------------- K7: out = BN(w_proj @ O1), bf16 MFMA ----------------
__global__ __launch_bounds__(256) void k_proj(const float* __restrict__ O1,
                                              const float* __restrict__ w,
                                              const float* __restrict__ bnp,
                                              float* __restrict__ out) {
    const int b   = blockIdx.z;
    const int ocB = blockIdx.y * 128;
    const int nB  = blockIdx.x * 128;
    const int tid = threadIdx.x;
    const int wv  = tid >> 6, lane = tid & 63;
    const int wm = wv >> 1, wn = wv & 1;
    const int lm = lane & 15, lg = lane >> 4;

    __shared__ unsigned short As[128 * 40];
    __shared__ unsigned short Bs[128 * 40];
    __shared__ float inv_s[128], bias_s[128];

    if (tid < 128) {
        int oc = ocB + tid;
        float g = bnp[0 * NC + oc], be = bnp[1 * NC + oc];
        float m = bnp[2 * NC + oc], vv = bnp[3 * NC + oc];
        float inv = g * rsqrtf(vv + EPSF);
        inv_s[tid] = inv;
        bias_s[tid] = be - m * inv;
    }

    f32x4 acc[4][4];
    #pragma unroll
    for (int i = 0; i < 4; ++i)
        #pragma unroll
        for (int j = 0; j < 4; ++j)
            acc[i][j] = (f32x4){0.f, 0.f, 0.f, 0.f};

    const int arow = tid >> 1, akh = (tid & 1) * 16;
    const int bn_ = tid & 127, bkh = (tid >> 7) * 16;

    for (int k0 = 0; k0 < 256; k0 += 32) {
        {
            const float* wp = w + (size_t)(ocB + arow) * 256 + k0 + akh;
            float4 f0 = reinterpret_cast<const float4*>(wp)[0];
            float4 f1 = reinterpret_cast<const float4*>(wp)[1];
            float4 f2 = reinterpret_cast<const float4*>(wp)[2];
            float4 f3 = reinterpret_cast<const float4*>(wp)[3];
            union { unsigned short u[16]; bf16x8 v[2]; } pk;
            pk.u[0]=f2bf(f0.x); pk.u[1]=f2bf(f0.y); pk.u[2]=f2bf(f0.z); pk.u[3]=f2bf(f0.w);
            pk.u[4]=f2bf(f1.x); pk.u[5]=f2bf(f1.y); pk.u[6]=f2bf(f1.z); pk.u[7]=f2bf(f1.w);
            pk.u[8]=f2bf(f2.x); pk.u[9]=f2bf(f2.y); pk.u[10]=f2bf(f2.z); pk.u[11]=f2bf(f2.w);
            pk.u[12]=f2bf(f3.x); pk.u[13]=f2bf(f3.y); pk.u[14]=f2bf(f3.z); pk.u[15]=f2bf(f3.w);
            *reinterpret_cast<bf16x8*>(&As[arow * 40 + akh]) = pk.v[0];
            *reinterpret_cast<bf16x8*>(&As[arow * 40 + akh + 8]) = pk.v[1];
        }
        {
            const float* xp = O1 + ((size_t)b * NC + k0 + bkh) * NHW + nB + bn_;
            float t[16];
            #pragma unroll
            for (int i = 0; i < 16; ++i) t[i] = xp[(size_t)i * NHW];
            union { unsigned short u[16]; bf16x8 v[2]; } pk;
            #pragma unroll
            for (int i = 0; i < 16; ++i) pk.u[i] = f2bf(t[i]);
            *reinterpret_cast<bf16x8*>(&Bs[bn_ * 40 + bkh]) = pk.v[0];
            *reinterpret_cast<bf16x8*>(&Bs[bn_ * 40 + bkh + 8]) = pk.v[1];
        }
        __syncthreads();

        bf16x8 af[4], bfr[4];
        #pragma unroll
        for (int mi = 0; mi < 4; ++mi)
            af[mi] = *reinterpret_cast<const bf16x8*>(&As[(wm * 64 + mi * 16 + lm) * 40 + lg * 8]);
        #pragma unroll
        for (int ni = 0; ni < 4; ++ni)
            bfr[ni] = *reinterpret_cast<const bf16x8*>(&Bs[(wn * 64 + ni * 16 + lm) * 40 + lg * 8]);
        #pragma unroll
        for (int mi = 0; mi < 4; ++mi)
            #pragma unroll
            for (int ni = 0; ni < 4; ++ni)
                acc[mi][ni] = __builtin_amdgcn_mfma_f32_16x16x32_bf16(af[mi], bfr[ni], acc[mi][ni], 0, 0, 0);
        __syncthreads();
    }

    float* dstb = out + ((size_t)b * NC + ocB) * NHW + nB;
    #pragma unroll
    for (int mi = 0; mi < 4; ++mi) {
        int lo_base = wm * 64 + mi * 16 + lg * 4;
        #pragma unroll
        for (int r = 0; r < 4; ++r) {
            int lo = lo_base + r;
            float inv = inv_s[lo], bias = bias_s[lo];
            #pragma unroll
            for (int ni = 0; ni < 4; ++ni) {
                int n = wn * 64 + ni * 16 + lm;
                dstb[(size_t)lo * NHW + n] = acc[mi][ni][r] * inv + bias;
            }
        }
    }
}

extern "C" void kernel_launch(void* const* d_in, const int* in_sizes, int n_in,
                              void* d_out, int out_size, void* d_ws, size_t ws_size,
                              hipStream_t stream) {
    (void)in_sizes; (void)n_in; (void)out_size; (void)ws_size;
    const float* x       = (const float*)d_in[0];
    const float* w_qkv   = (const float*)d_in[1];
    const float* bn_qkv  = (const float*)d_in[2];
    const float* w_cv1   = (const float*)d_in[3];
    const float* bn_cv1  = (const float*)d_in[4];
    const float* w_cv2   = (const float*)d_in[5];
    const float* bn_cv2  = (const float*)d_in[6];
    const float* w_proj  = (const float*)d_in[7];
    const float* bn_proj = (const float*)d_in[8];
    const float* w_pe    = (const float*)d_in[9];
    const float* bn_pe   = (const float*)d_in[10];
    float* out = (float*)d_out;

    float* ws = (float*)d_ws;
    float* Q    = ws;
    float* Kb   = ws + SZQ;
    float* Vb   = ws + 2 * SZQ;
    float* O1   = Kb;                                  // K dead after k_attn_part
    float* Aa   = ws + 3 * SZQ;
    float* AT   = Aa + (size_t)NB * NC * NAG;          // 131072
    float* Pm   = AT + (size_t)NB * NHEAD * NAG * NKD; // 131072
    float* Pl   = Pm + (size_t)NB * NHEAD * NSPLIT * NAG;   // 65536
    float* Pacc = Pl + (size_t)NB * NHEAD * NSPLIT * NAG;   // 65536

    k_qkv<<<dim3(32, 6, NB), 256, 0, stream>>>(x, w_qkv, bn_qkv, Q);
    k_gates<<<NB * HDIM, 256, 0, stream>>>(Kb, Vb, w_cv1, bn_cv1, w_cv2, bn_cv2);
    k_pool<<<NB * NC, 64, 0, stream>>>(Q, Aa);
    k_attn_part<<<NB * NHEAD * NSPLIT, 256, 0, stream>>>(Kb, Vb, Aa, Pm, Pl, Pacc);
    k_attn_comb<<<NB * NHEAD, 256, 0, stream>>>(Pm, Pl, Pacc, AT);
    k_qattn<<<dim3(32, 64), 256, 0, stream>>>(Q, Aa, AT, O1);
    k_pe<<<NB * NC, 256, 0, stream>>>(Vb, w_pe, bn_pe, O1);
    k_proj<<<dim3(32, 2, NB), 256, 0, stream>>>(O1, w_proj, bn_proj, out);
}

// Round 7
// 169.424 us; speedup vs baseline: 6.8429x; 1.1977x over previous
//
#include <hip/hip_runtime.h>
#include <hip/hip_bf16.h>

#define NB 8
#define NC 256
#define NHW 4096       // H*W
#define HDIM 64
#define WDIM 64
#define NHEAD 8
#define NKD 32
#define NAG 64
#define NMIP 8
#define NSPLIT 16
#define EPSF 1e-5f
#define FSCALE 0.17677669529663687f  // 32^-0.5
#define SZQ ((size_t)NB * NC * NHW)

typedef __attribute__((ext_vector_type(8))) short bf16x8;
typedef __attribute__((ext_vector_type(8))) unsigned short u16x8;
typedef __attribute__((ext_vector_type(4))) float f32x4;

__device__ __forceinline__ unsigned short f2bf(float f) {
    union { float f; unsigned u; } v; v.f = f;
    unsigned r = v.u + 0x7FFF + ((v.u >> 16) & 1);
    return (unsigned short)(r >> 16);
}
__device__ __forceinline__ float b2f(unsigned short u) {
    union { unsigned u32; float f; } v; v.u32 = ((unsigned)u) << 16; return v.f;
}

// ---------------- K1: qkv = BN(w_qkv @ x), bf16 MFMA, bf16 out ----------------
__global__ __launch_bounds__(256) void k_qkv(const float* __restrict__ x,
                                             const float* __restrict__ w,
                                             const float* __restrict__ bnp,
                                             unsigned short* __restrict__ Qb,
                                             unsigned short* __restrict__ Kb,
                                             unsigned short* __restrict__ Vb) {
    const int b   = blockIdx.z;
    const int ocB = blockIdx.y * 128;
    const int nB  = blockIdx.x * 128;
    const int tid = threadIdx.x;
    const int wv  = tid >> 6, lane = tid & 63;
    const int wm = wv >> 1, wn = wv & 1;
    const int lm = lane & 15, lg = lane >> 4;

    __shared__ unsigned short As[128 * 40];   // [m][k]
    __shared__ unsigned short Bs[128 * 40];   // [n][k]
    __shared__ float inv_s[128], bias_s[128];

    if (tid < 128) {
        int oc = ocB + tid;
        float g = bnp[0 * 768 + oc], be = bnp[1 * 768 + oc];
        float m = bnp[2 * 768 + oc], vv = bnp[3 * 768 + oc];
        float inv = g * rsqrtf(vv + EPSF);
        inv_s[tid] = inv;
        bias_s[tid] = be - m * inv;
    }

    f32x4 acc[4][4];
    #pragma unroll
    for (int i = 0; i < 4; ++i)
        #pragma unroll
        for (int j = 0; j < 4; ++j)
            acc[i][j] = (f32x4){0.f, 0.f, 0.f, 0.f};

    const int arow = tid >> 1, akh = (tid & 1) * 16;
    const int bn_ = tid & 127, bkh = (tid >> 7) * 16;

    for (int k0 = 0; k0 < 256; k0 += 32) {
        {
            const float* wp = w + (size_t)(ocB + arow) * 256 + k0 + akh;
            float4 f0 = reinterpret_cast<const float4*>(wp)[0];
            float4 f1 = reinterpret_cast<const float4*>(wp)[1];
            float4 f2 = reinterpret_cast<const float4*>(wp)[2];
            float4 f3 = reinterpret_cast<const float4*>(wp)[3];
            union { unsigned short u[16]; bf16x8 v[2]; } pk;
            pk.u[0]=f2bf(f0.x); pk.u[1]=f2bf(f0.y); pk.u[2]=f2bf(f0.z); pk.u[3]=f2bf(f0.w);
            pk.u[4]=f2bf(f1.x); pk.u[5]=f2bf(f1.y); pk.u[6]=f2bf(f1.z); pk.u[7]=f2bf(f1.w);
            pk.u[8]=f2bf(f2.x); pk.u[9]=f2bf(f2.y); pk.u[10]=f2bf(f2.z); pk.u[11]=f2bf(f2.w);
            pk.u[12]=f2bf(f3.x); pk.u[13]=f2bf(f3.y); pk.u[14]=f2bf(f3.z); pk.u[15]=f2bf(f3.w);
            *reinterpret_cast<bf16x8*>(&As[arow * 40 + akh]) = pk.v[0];
            *reinterpret_cast<bf16x8*>(&As[arow * 40 + akh + 8]) = pk.v[1];
        }
        {
            const float* xp = x + ((size_t)b * NC + k0 + bkh) * NHW + nB + bn_;
            float t[16];
            #pragma unroll
            for (int i = 0; i < 16; ++i) t[i] = xp[(size_t)i * NHW];
            union { unsigned short u[16]; bf16x8 v[2]; } pk;
            #pragma unroll
            for (int i = 0; i < 16; ++i) pk.u[i] = f2bf(t[i]);
            *reinterpret_cast<bf16x8*>(&Bs[bn_ * 40 + bkh]) = pk.v[0];
            *reinterpret_cast<bf16x8*>(&Bs[bn_ * 40 + bkh + 8]) = pk.v[1];
        }
        __syncthreads();

        bf16x8 af[4], bfr[4];
        #pragma unroll
        for (int mi = 0; mi < 4; ++mi)
            af[mi] = *reinterpret_cast<const bf16x8*>(&As[(wm * 64 + mi * 16 + lm) * 40 + lg * 8]);
        #pragma unroll
        for (int ni = 0; ni < 4; ++ni)
            bfr[ni] = *reinterpret_cast<const bf16x8*>(&Bs[(wn * 64 + ni * 16 + lm) * 40 + lg * 8]);
        #pragma unroll
        for (int mi = 0; mi < 4; ++mi)
            #pragma unroll
            for (int ni = 0; ni < 4; ++ni)
                acc[mi][ni] = __builtin_amdgcn_mfma_f32_16x16x32_bf16(af[mi], bfr[ni], acc[mi][ni], 0, 0, 0);
        __syncthreads();
    }

    #pragma unroll
    for (int mi = 0; mi < 4; ++mi) {
        #pragma unroll
        for (int r = 0; r < 4; ++r) {
            int lo = wm * 64 + mi * 16 + lg * 4 + r;
            int oc = ocB + lo;
            float inv = inv_s[lo], bias = bias_s[lo];
            unsigned short* base; int oc2;
            if (oc < 256)      { base = Qb; oc2 = oc; }
            else if (oc < 512) { base = Kb; oc2 = oc - 256; }
            else               { base = Vb; oc2 = oc - 512; }
            unsigned short* dp = base + ((size_t)b * NC + oc2) * NHW + nB;
            #pragma unroll
            for (int ni = 0; ni < 4; ++ni) {
                int n = wn * 64 + ni * 16 + lm;
                dp[n] = f2bf(acc[mi][ni][r] * inv + bias);
            }
        }
    }
}

// ---------------- K2a: per-(b,c,h) W-means of K and V ----------------
__global__ __launch_bounds__(256) void k_means(const unsigned short* __restrict__ K,
                                               const unsigned short* __restrict__ V,
                                               float* __restrict__ AMK,
                                               float* __restrict__ AMV) {
    const int bc = blockIdx.x;           // b*NC + c
    const int b = bc >> 8;
    const int c = bc & 255;
    const int t = threadIdx.x;
    #pragma unroll
    for (int pass = 0; pass < 2; ++pass) {
        const unsigned short* p = (pass ? V : K) + (size_t)bc * NHW + t * 16;
        u16x8 a0 = *reinterpret_cast<const u16x8*>(p);
        u16x8 a1 = *reinterpret_cast<const u16x8*>(p + 8);
        float s = 0.f;
        #pragma unroll
        for (int i = 0; i < 8; ++i) s += b2f(a0[i]);
        #pragma unroll
        for (int i = 0; i < 8; ++i) s += b2f(a1[i]);
        s += __shfl_xor(s, 1);
        s += __shfl_xor(s, 2);
        if ((t & 3) == 0)
            (pass ? AMV : AMK)[((size_t)b * HDIM + (t >> 2)) * NC + c] = s * (1.0f / 64.0f);
    }
}

// ---------------- K2b: SE gate values per (b,h) ----------------
__global__ __launch_bounds__(256) void k_gatecomp(const float* __restrict__ AMK,
                                                  const float* __restrict__ AMV,
                                                  const float* __restrict__ w1,
                                                  const float* __restrict__ bn1,
                                                  const float* __restrict__ w2,
                                                  const float* __restrict__ bn2,
                                                  float* __restrict__ GK,
                                                  float* __restrict__ GV) {
    const int b = blockIdx.x >> 6;
    const int h = blockIdx.x & 63;
    const int c = threadIdx.x;
    __shared__ float am[NC];
    __shared__ float m1[NMIP];
    for (int pass = 0; pass < 2; ++pass) {
        am[c] = (pass ? AMV : AMK)[((size_t)b * HDIM + h) * NC + c];
        __syncthreads();
        if (c < NMIP) {
            float t = 0.f;
            for (int cc = 0; cc < NC; ++cc) t += w1[c * NC + cc] * am[cc];
            float g = bn1[0 * NMIP + c], be = bn1[1 * NMIP + c];
            float mm = bn1[2 * NMIP + c], vv = bn1[3 * NMIP + c];
            float inv = g * rsqrtf(vv + EPSF);
            m1[c] = t * inv + (be - mm * inv);
        }
        __syncthreads();
        {
            float t = 0.f;
            #pragma unroll
            for (int j = 0; j < NMIP; ++j) t += w2[c * NMIP + j] * m1[j];
            float g = bn2[0 * NC + c], be = bn2[1 * NC + c];
            float mm = bn2[2 * NC + c], vv = bn2[3 * NC + c];
            float inv = g * rsqrtf(vv + EPSF);
            (pass ? GV : GK)[((size_t)b * NC + c) * HDIM + h] = t * inv + (be - mm * inv);
        }
        __syncthreads();
    }
}

// ---------------- K3: 8x8 block pool of Q -> agent tokens ----------------
__global__ __launch_bounds__(64) void k_pool(const unsigned short* __restrict__ Q,
                                             float* __restrict__ A_) {
    const int bc = blockIdx.x;
    const int ag = threadIdx.x;
    const int ph = ag >> 3, pw = ag & 7;
    const unsigned short* src = Q + (size_t)bc * NHW;
    float s = 0.f;
    #pragma unroll
    for (int i = 0; i < 8; ++i) {
        u16x8 v = *reinterpret_cast<const u16x8*>(&src[(ph * 8 + i) * WDIM + pw * 8]);
        #pragma unroll
        for (int j = 0; j < 8; ++j) s += b2f(v[j]);
    }
    A_[(size_t)bc * NAG + ag] = s * (1.0f / 64.0f);
}

// ---------------- K4a: agent attn partials (split-N flash), bf16 MFMA, gate-fused ----------------
__global__ __launch_bounds__(256) void k_attn_part(const unsigned short* __restrict__ K,
                                                   const unsigned short* __restrict__ V,
                                                   const float* __restrict__ A_,
                                                   const float* __restrict__ GK,
                                                   const float* __restrict__ GV,
                                                   float* __restrict__ Pm,
                                                   float* __restrict__ Pl,
                                                   float* __restrict__ Pacc) {
    const int bh = blockIdx.x >> 4;
    const int ns = blockIdx.x & (NSPLIT - 1);
    const int b = bh >> 3, h = bh & 7;
    const int tid = threadIdx.x;
    const int wv = tid >> 6, lane = tid & 63;
    const int lm = lane & 15, lg = lane >> 4;

    __shared__ unsigned short a_s[64 * 40];   // [ag][d]
    __shared__ unsigned short kt_s[64 * 40];  // [col][d]
    __shared__ unsigned short vt_s[32 * 72];  // [dd][col]
    __shared__ unsigned short Ps[64 * 72];    // [ag][col]

    {
        int d = tid >> 3, ag0 = (tid & 7) * 8;
        const float* ap = A_ + ((size_t)(b * NC + h * NKD + d)) * NAG + ag0;
        float4 v0 = reinterpret_cast<const float4*>(ap)[0];
        float4 v1 = reinterpret_cast<const float4*>(ap)[1];
        float t8[8] = {v0.x, v0.y, v0.z, v0.w, v1.x, v1.y, v1.z, v1.w};
        #pragma unroll
        for (int i = 0; i < 8; ++i)
            a_s[(ag0 + i) * 40 + d] = f2bf(t8[i] * FSCALE);
    }

    float mrow[4], lrow[4];
    f32x4 acc[2];
    #pragma unroll
    for (int r = 0; r < 4; ++r) { mrow[r] = -1e30f; lrow[r] = 0.f; }
    acc[0] = (f32x4){0.f, 0.f, 0.f, 0.f};
    acc[1] = (f32x4){0.f, 0.f, 0.f, 0.f};

    const int colbase = ns * (NHW / NSPLIT);
    const unsigned short* Kp = K + (size_t)(b * NC + h * NKD) * NHW + colbase;
    const unsigned short* Vp = V + (size_t)(b * NC + h * NKD) * NHW + colbase;
    const int sd = tid >> 3;                       // staging channel d
    const size_t gbase = ((size_t)(b * NC + h * NKD + sd)) * HDIM;
    __syncthreads();

    for (int nt = 0; nt < 4; ++nt) {
        const int gh = ns * 4 + nt;                // spatial row of this tile
        // stage K tile transposed + gated
        {
            int c0 = tid & 7;
            float gk = GK[gbase + gh];
            const unsigned short* kp = Kp + (size_t)sd * NHW + nt * 64 + c0;
            #pragma unroll
            for (int i = 0; i < 8; ++i)
                kt_s[(c0 + 8 * i) * 40 + sd] = f2bf(b2f(kp[8 * i]) * gk);
        }
        // stage V tile straight + gated
        {
            int c0 = (tid & 7) * 8;
            float gv = GV[gbase + gh];
            const unsigned short* vp = Vp + (size_t)sd * NHW + nt * 64 + c0;
            u16x8 vr = *reinterpret_cast<const u16x8*>(vp);
            union { unsigned short u[8]; bf16x8 v; } pk;
            #pragma unroll
            for (int i = 0; i < 8; ++i) pk.u[i] = f2bf(b2f(vr[i]) * gv);
            *reinterpret_cast<bf16x8*>(&vt_s[sd * 72 + c0]) = pk.v;
        }
        __syncthreads();

        f32x4 s[4];
        {
            bf16x8 af = *reinterpret_cast<const bf16x8*>(&a_s[(wv * 16 + lm) * 40 + lg * 8]);
            #pragma unroll
            for (int ni = 0; ni < 4; ++ni) {
                bf16x8 kf = *reinterpret_cast<const bf16x8*>(&kt_s[(ni * 16 + lm) * 40 + lg * 8]);
                s[ni] = __builtin_amdgcn_mfma_f32_16x16x32_bf16(
                    af, kf, (f32x4){0.f, 0.f, 0.f, 0.f}, 0, 0, 0);
            }
        }

        float fsc[4];
        #pragma unroll
        for (int r = 0; r < 4; ++r) {
            float mx = fmaxf(fmaxf(s[0][r], s[1][r]), fmaxf(s[2][r], s[3][r]));
            mx = fmaxf(mx, __shfl_xor(mx, 1));
            mx = fmaxf(mx, __shfl_xor(mx, 2));
            mx = fmaxf(mx, __shfl_xor(mx, 4));
            mx = fmaxf(mx, __shfl_xor(mx, 8));
            float mnew = fmaxf(mrow[r], mx);
            fsc[r] = __expf(mrow[r] - mnew);
            mrow[r] = mnew;
            int agrow = wv * 16 + lg * 4 + r;
            float ps = 0.f;
            #pragma unroll
            for (int ni = 0; ni < 4; ++ni) {
                float p = __expf(s[ni][r] - mnew);
                Ps[agrow * 72 + ni * 16 + lm] = f2bf(p);
                ps += p;
            }
            ps += __shfl_xor(ps, 1);
            ps += __shfl_xor(ps, 2);
            ps += __shfl_xor(ps, 4);
            ps += __shfl_xor(ps, 8);
            lrow[r] = lrow[r] * fsc[r] + ps;
        }
        #pragma unroll
        for (int ni = 0; ni < 2; ++ni)
            #pragma unroll
            for (int r = 0; r < 4; ++r)
                acc[ni][r] *= fsc[r];
        __syncthreads();

        #pragma unroll
        for (int kk = 0; kk < 2; ++kk) {
            bf16x8 pa = *reinterpret_cast<const bf16x8*>(&Ps[(wv * 16 + lm) * 72 + kk * 32 + lg * 8]);
            #pragma unroll
            for (int ni = 0; ni < 2; ++ni) {
                bf16x8 vb = *reinterpret_cast<const bf16x8*>(&vt_s[(ni * 16 + lm) * 72 + kk * 32 + lg * 8]);
                acc[ni] = __builtin_amdgcn_mfma_f32_16x16x32_bf16(pa, vb, acc[ni], 0, 0, 0);
            }
        }
        __syncthreads();
    }

    const size_t pbase = (size_t)(bh * NSPLIT + ns) * NAG;
    #pragma unroll
    for (int r = 0; r < 4; ++r) {
        int ag = wv * 16 + lg * 4 + r;
        #pragma unroll
        for (int ni = 0; ni < 2; ++ni)
            Pacc[(pbase + ag) * NKD + ni * 16 + lm] = acc[ni][r];
        if (lm == 0) {
            Pm[pbase + ag] = mrow[r];
            Pl[pbase + ag] = lrow[r];
        }
    }
}

// ---------------- K4b: combine partials ----------------
__global__ __launch_bounds__(256) void k_attn_comb(const float* __restrict__ Pm,
                                                   const float* __restrict__ Pl,
                                                   const float* __restrict__ Pacc,
                                                   float* __restrict__ AT) {
    const int bh = blockIdx.x;
    const int tid = threadIdx.x;
    const int ag = tid >> 2, jg = tid & 3;
    float m = -1e30f;
    #pragma unroll
    for (int ns = 0; ns < NSPLIT; ++ns)
        m = fmaxf(m, Pm[(size_t)(bh * NSPLIT + ns) * NAG + ag]);
    float l = 0.f;
    float acc[8] = {};
    for (int ns = 0; ns < NSPLIT; ++ns) {
        size_t pb = (size_t)(bh * NSPLIT + ns) * NAG + ag;
        float f = __expf(Pm[pb] - m);
        l += Pl[pb] * f;
        const float* pp = Pacc + pb * NKD + jg * 8;
        #pragma unroll
        for (int i = 0; i < 8; ++i) acc[i] += pp[i] * f;
    }
    float linv = 1.0f / l;
    #pragma unroll
    for (int i = 0; i < 8; ++i)
        AT[((size_t)bh * NAG + ag) * NKD + jg * 8 + i] = acc[i] * linv;
}

// ---------------- K5: out1 = softmax_ag(q^T a) @ attn, bf16 MFMA ----------------
__global__ __launch_bounds__(256) void k_qattn(const unsigned short* __restrict__ Q,
                                               const float* __restrict__ A_,
                                               const float* __restrict__ AT,
                                               float* __restrict__ O1) {
    const int bh = blockIdx.y;
    const int b = bh >> 3, h = bh & 7;
    const int n0 = blockIdx.x * 128;
    const int tid = threadIdx.x;
    const int wv = tid >> 6, lane = tid & 63;
    const int lm = lane & 15, lg = lane >> 4;

    __shared__ unsigned short Qs[128][40];
    __shared__ unsigned short Ags[64][40];
    __shared__ unsigned short ATs[32][72];
    __shared__ unsigned short Ps[128][72];

    const unsigned short* Qbase = Q + ((size_t)b * NC + h * NKD) * NHW;

    {
        int d = tid >> 3, nb_ = (tid & 7) * 16;
        const unsigned short* qp = Qbase + (size_t)d * NHW + n0 + nb_;
        u16x8 v0 = *reinterpret_cast<const u16x8*>(qp);
        u16x8 v1 = *reinterpret_cast<const u16x8*>(qp + 8);
        #pragma unroll
        for (int i = 0; i < 8; ++i) Qs[nb_ + i][d] = v0[i];
        #pragma unroll
        for (int i = 0; i < 8; ++i) Qs[nb_ + 8 + i][d] = v1[i];
    }
    if (tid < 128) {
        int d = tid >> 2, ag0 = (tid & 3) * 16;
        const float* ap = A_ + ((size_t)(b * NC + h * NKD + d)) * NAG + ag0;
        #pragma unroll
        for (int i = 0; i < 16; ++i) Ags[ag0 + i][d] = f2bf(ap[i] * FSCALE);
    }
    if (tid < 128) {
        int ag = tid >> 1, d0 = (tid & 1) * 16;
        const float* atp = AT + ((size_t)bh * NAG + ag) * NKD + d0;
        #pragma unroll
        for (int i = 0; i < 16; ++i) ATs[d0 + i][ag] = f2bf(atp[i]);
    }
    __syncthreads();

    f32x4 s[2][4];
    #pragma unroll
    for (int mi = 0; mi < 2; ++mi)
        #pragma unroll
        for (int ni = 0; ni < 4; ++ni)
            s[mi][ni] = (f32x4){0.f, 0.f, 0.f, 0.f};
    {
        bf16x8 qa[2], ab[4];
        #pragma unroll
        for (int mi = 0; mi < 2; ++mi)
            qa[mi] = *reinterpret_cast<const bf16x8*>(&Qs[wv * 32 + mi * 16 + lm][lg * 8]);
        #pragma unroll
        for (int ni = 0; ni < 4; ++ni)
            ab[ni] = *reinterpret_cast<const bf16x8*>(&Ags[ni * 16 + lm][lg * 8]);
        #pragma unroll
        for (int mi = 0; mi < 2; ++mi)
            #pragma unroll
            for (int ni = 0; ni < 4; ++ni)
                s[mi][ni] = __builtin_amdgcn_mfma_f32_16x16x32_bf16(qa[mi], ab[ni], s[mi][ni], 0, 0, 0);
    }

    float lsum[2][4];
    #pragma unroll
    for (int mi = 0; mi < 2; ++mi) {
        #pragma unroll
        for (int r = 0; r < 4; ++r) {
            float mx = fmaxf(fmaxf(s[mi][0][r], s[mi][1][r]), fmaxf(s[mi][2][r], s[mi][3][r]));
            mx = fmaxf(mx, __shfl_xor(mx, 1));
            mx = fmaxf(mx, __shfl_xor(mx, 2));
            mx = fmaxf(mx, __shfl_xor(mx, 4));
            mx = fmaxf(mx, __shfl_xor(mx, 8));
            int nrow = wv * 32 + mi * 16 + lg * 4 + r;
            float ls = 0.f;
            #pragma unroll
            for (int ni = 0; ni < 4; ++ni) {
                float p = __expf(s[mi][ni][r] - mx);
                ls += p;
                Ps[nrow][ni * 16 + lm] = f2bf(p);
            }
            ls += __shfl_xor(ls, 1);
            ls += __shfl_xor(ls, 2);
            ls += __shfl_xor(ls, 4);
            ls += __shfl_xor(ls, 8);
            lsum[mi][r] = ls;
        }
    }
    __syncthreads();

    f32x4 o[2][2];
    #pragma unroll
    for (int mi = 0; mi < 2; ++mi)
        #pragma unroll
        for (int ni = 0; ni < 2; ++ni)
            o[mi][ni] = (f32x4){0.f, 0.f, 0.f, 0.f};
    #pragma unroll
    for (int kk = 0; kk < 2; ++kk) {
        bf16x8 pa[2], vb[2];
        #pragma unroll
        for (int mi = 0; mi < 2; ++mi)
            pa[mi] = *reinterpret_cast<const bf16x8*>(&Ps[wv * 32 + mi * 16 + lm][kk * 32 + lg * 8]);
        #pragma unroll
        for (int ni = 0; ni < 2; ++ni)
            vb[ni] = *reinterpret_cast<const bf16x8*>(&ATs[ni * 16 + lm][kk * 32 + lg * 8]);
        #pragma unroll
        for (int mi = 0; mi < 2; ++mi)
            #pragma unroll
            for (int ni = 0; ni < 2; ++ni)
                o[mi][ni] = __builtin_amdgcn_mfma_f32_16x16x32_bf16(pa[mi], vb[ni], o[mi][ni], 0, 0, 0);
    }

    float* obase = O1 + ((size_t)b * NC + h * NKD) * NHW + n0;
    #pragma unroll
    for (int mi = 0; mi < 2; ++mi) {
        #pragma unroll
        for (int r = 0; r < 4; ++r) {
            float rl = 1.0f / lsum[mi][r];
            int n = wv * 32 + mi * 16 + lg * 4 + r;
            #pragma unroll
            for (int ni = 0; ni < 2; ++ni) {
                int d = ni * 16 + lm;
                obase[(size_t)d * NHW + n] = o[mi][ni][r] * rl;
            }
        }
    }
}

// ---------------- K6: O1 += BN(depthwise 3x3 conv of gated V) ----------------
__global__ __launch_bounds__(256) void k_pe(const unsigned short* __restrict__ V,
                                            const float* __restrict__ GV,
                                            const float* __restrict__ wpe,
                                            const float* __restrict__ bnp,
                                            float* __restrict__ O1) {
    const int bc = blockIdx.x;
    const int c = bc & (NC - 1);
    __shared__ float gv_s[HDIM];
    if (threadIdx.x < HDIM) gv_s[threadIdx.x] = GV[(size_t)bc * HDIM + threadIdx.x];
    float wreg[9];
    #pragma unroll
    for (int i = 0; i < 9; ++i) wreg[i] = wpe[c * 9 + i];
    float g = bnp[0 * NC + c], be = bnp[1 * NC + c];
    float m = bnp[2 * NC + c], vv = bnp[3 * NC + c];
    float inv = g * rsqrtf(vv + EPSF);
    float bias = be - m * inv;
    const unsigned short* src = V + (size_t)bc * NHW;
    float* dst = O1 + (size_t)bc * NHW;
    __syncthreads();
    for (int idx = threadIdx.x; idx < NHW; idx += 256) {
        int h = idx >> 6, w = idx & 63;
        float s = 0.f;
        #pragma unroll
        for (int kh = 0; kh < 3; ++kh) {
            int hh = h + kh - 1;
            if (hh < 0 || hh >= HDIM) continue;
            float rs = 0.f;
            #pragma unroll
            for (int kw = 0; kw < 3; ++kw) {
                int ww = w + kw - 1;
                if (ww < 0 || ww >= WDIM) continue;
                rs = fmaf(wreg[kh * 3 + kw], b2f(src[hh * WDIM + ww]), rs);
            }
            s = fmaf(rs, gv_s[hh], s);
        }
        dst[idx] += s * inv + bias;
    }
}

// ---------------- K7: out = BN(w_proj @ O1), bf16 MFMA ----------------
__global__ __launch_bounds__(256) void k_proj(const float* __restrict__ O1,
                                              const float* __restrict__ w,
                                              const float* __restrict__ bnp,
                                              float* __restrict__ out) {
    const int b   = blockIdx.z;
    const int ocB = blockIdx.y * 128;
    const int nB  = blockIdx.x * 128;
    const int tid = threadIdx.x;
    const int wv  = tid >> 6, lane = tid & 63;
    const int wm = wv >> 1, wn = wv & 1;
    const int lm = lane & 15, lg = lane >> 4;

    __shared__ unsigned short As[128 * 40];
    __shared__ unsigned short Bs[128 * 40];
    __shared__ float inv_s[128], bias_s[128];

    if (tid < 128) {
        int oc = ocB + tid;
        float g = bnp[0 * NC + oc], be = bnp[1 * NC + oc];
        float m = bnp[2 * NC + oc], vv = bnp[3 * NC + oc];
        float inv = g * rsqrtf(vv + EPSF);
        inv_s[tid] = inv;
        bias_s[tid] = be - m * inv;
    }

    f32x4 acc[4][4];
    #pragma unroll
    for (int i = 0; i < 4; ++i)
        #pragma unroll
        for (int j = 0; j < 4; ++j)
            acc[i][j] = (f32x4){0.f, 0.f, 0.f, 0.f};

    const int arow = tid >> 1, akh = (tid & 1) * 16;
    const int bn_ = tid & 127, bkh = (tid >> 7) * 16;

    for (int k0 = 0; k0 < 256; k0 += 32) {
        {
            const float* wp = w + (size_t)(ocB + arow) * 256 + k0 + akh;
            float4 f0 = reinterpret_cast<const float4*>(wp)[0];
            float4 f1 = reinterpret_cast<const float4*>(wp)[1];
            float4 f2 = reinterpret_cast<const float4*>(wp)[2];
            float4 f3 = reinterpret_cast<const float4*>(wp)[3];
            union { unsigned short u[16]; bf16x8 v[2]; } pk;
            pk.u[0]=f2bf(f0.x); pk.u[1]=f2bf(f0.y); pk.u[2]=f2bf(f0.z); pk.u[3]=f2bf(f0.w);
            pk.u[4]=f2bf(f1.x); pk.u[5]=f2bf(f1.y); pk.u[6]=f2bf(f1.z); pk.u[7]=f2bf(f1.w);
            pk.u[8]=f2bf(f2.x); pk.u[9]=f2bf(f2.y); pk.u[10]=f2bf(f2.z); pk.u[11]=f2bf(f2.w);
            pk.u[12]=f2bf(f3.x); pk.u[13]=f2bf(f3.y); pk.u[14]=f2bf(f3.z); pk.u[15]=f2bf(f3.w);
            *reinterpret_cast<bf16x8*>(&As[arow * 40 + akh]) = pk.v[0];
            *reinterpret_cast<bf16x8*>(&As[arow * 40 + akh + 8]) = pk.v[1];
        }
        {
            const float* xp = O1 + ((size_t)b * NC + k0 + bkh) * NHW + nB + bn_;
            float t[16];
            #pragma unroll
            for (int i = 0; i < 16; ++i) t[i] = xp[(size_t)i * NHW];
            union { unsigned short u[16]; bf16x8 v[2]; } pk;
            #pragma unroll
            for (int i = 0; i < 16; ++i) pk.u[i] = f2bf(t[i]);
            *reinterpret_cast<bf16x8*>(&Bs[bn_ * 40 + bkh]) = pk.v[0];
            *reinterpret_cast<bf16x8*>(&Bs[bn_ * 40 + bkh + 8]) = pk.v[1];
        }
        __syncthreads();

        bf16x8 af[4], bfr[4];
        #pragma unroll
        for (int mi = 0; mi < 4; ++mi)
            af[mi] = *reinterpret_cast<const bf16x8*>(&As[(wm * 64 + mi * 16 + lm) * 40 + lg * 8]);
        #pragma unroll
        for (int ni = 0; ni < 4; ++ni)
            bfr[ni] = *reinterpret_cast<const bf16x8*>(&Bs[(wn * 64 + ni * 16 + lm) * 40 + lg * 8]);
        #pragma unroll
        for (int mi = 0; mi < 4; ++mi)
            #pragma unroll
            for (int ni = 0; ni < 4; ++ni)
                acc[mi][ni] = __builtin_amdgcn_mfma_f32_16x16x32_bf16(af[mi], bfr[ni], acc[mi][ni], 0, 0, 0);
        __syncthreads();
    }

    float* dstb = out + ((size_t)b * NC + ocB) * NHW + nB;
    #pragma unroll
    for (int mi = 0; mi < 4; ++mi) {
        int lo_base = wm * 64 + mi * 16 + lg * 4;
        #pragma unroll
        for (int r = 0; r < 4; ++r) {
            int lo = lo_base + r;
            float inv = inv_s[lo], bias = bias_s[lo];
            #pragma unroll
            for (int ni = 0; ni < 4; ++ni) {
                int n = wn * 64 + ni * 16 + lm;
                dstb[(size_t)lo * NHW + n] = acc[mi][ni][r] * inv + bias;
            }
        }
    }
}

extern "C" void kernel_launch(void* const* d_in, const int* in_sizes, int n_in,
                              void* d_out, int out_size, void* d_ws, size_t ws_size,
                              hipStream_t stream) {
    (void)in_sizes; (void)n_in; (void)out_size; (void)ws_size;
    const float* x       = (const float*)d_in[0];
    const float* w_qkv   = (const float*)d_in[1];
    const float* bn_qkv  = (const float*)d_in[2];
    const float* w_cv1   = (const float*)d_in[3];
    const float* bn_cv1  = (const float*)d_in[4];
    const float* w_cv2   = (const float*)d_in[5];
    const float* bn_cv2  = (const float*)d_in[6];
    const float* w_proj  = (const float*)d_in[7];
    const float* bn_proj = (const float*)d_in[8];
    const float* w_pe    = (const float*)d_in[9];
    const float* bn_pe   = (const float*)d_in[10];
    float* out = (float*)d_out;

    unsigned short* Qb = (unsigned short*)d_ws;
    unsigned short* Kb = Qb + SZQ;
    unsigned short* Vb = Kb + SZQ;
    float* O1   = (float*)(Vb + SZQ);
    float* Aa   = O1 + SZQ;
    float* AT   = Aa + (size_t)NB * NC * NAG;               // 131072
    float* Pm   = AT + (size_t)NB * NHEAD * NAG * NKD;      // 131072
    float* Pl   = Pm + (size_t)NB * NHEAD * NSPLIT * NAG;   // 65536
    float* Pacc = Pl + (size_t)NB * NHEAD * NSPLIT * NAG;   // 65536
    float* AMK  = Pacc + (size_t)NB * NHEAD * NSPLIT * NAG * NKD;  // 2.1M
    float* AMV  = AMK + (size_t)NB * HDIM * NC;             // 131072
    float* GK   = AMV + (size_t)NB * HDIM * NC;
    float* GV   = GK + (size_t)NB * NC * HDIM;

    k_qkv<<<dim3(32, 6, NB), 256, 0, stream>>>(x, w_qkv, bn_qkv, Qb, Kb, Vb);
    k_means<<<NB * NC, 256, 0, stream>>>(Kb, Vb, AMK, AMV);
    k_gatecomp<<<NB * HDIM, 256, 0, stream>>>(AMK, AMV, w_cv1, bn_cv1, w_cv2, bn_cv2, GK, GV);
    k_pool<<<NB * NC, 64, 0, stream>>>(Qb, Aa);
    k_attn_part<<<NB * NHEAD * NSPLIT, 256, 0, stream>>>(Kb, Vb, Aa, GK, GV, Pm, Pl, Pacc);
    k_attn_comb<<<NB * NHEAD, 256, 0, stream>>>(Pm, Pl, Pacc, AT);
    k_qattn<<<dim3(32, 64), 256, 0, stream>>>(Qb, Aa, AT, O1);
    k_pe<<<NB * NC, 256, 0, stream>>>(Vb, GV, w_pe, bn_pe, O1);
    k_proj<<<dim3(32, 2, NB), 256, 0, stream>>>(O1, w_proj, bn_proj, out);
}